// Round 13
// baseline (567.846 us; speedup 1.0000x reference)
//
#include <hip/hip_runtime.h>
#include <math.h>

typedef short s16x8 __attribute__((ext_vector_type(8)));
typedef float f32x4 __attribute__((ext_vector_type(4)));
typedef unsigned u32x4 __attribute__((ext_vector_type(4)));
typedef unsigned short u16;

#define S_LEN 2048
#define HID_DIM 4096
#define NH_Q 32
#define NKV_H 8
#define DHEAD 128

__device__ __forceinline__ u16 f2bf(float f) {
  unsigned u = __builtin_bit_cast(unsigned, f);
  u += 0x7fffu + ((u >> 16) & 1u);
  return (u16)(u >> 16);
}

// async global -> LDS, 16B per lane; lds base wave-uniform, lane*16 auto-offset
__device__ __forceinline__ void gload16(const u16* g, u16* l) {
  __builtin_amdgcn_global_load_lds(
      (const __attribute__((address_space(1))) void*)g,
      (__attribute__((address_space(3))) void*)l, 16, 0, 0);
}

// ---------------- f32 -> bf16 bulk convert (single region) ----------------
__global__ void cvt_kernel(const float* __restrict__ in, u16* __restrict__ out, int n4) {
  int stride = gridDim.x * blockDim.x;
  for (int i = blockIdx.x * blockDim.x + threadIdx.x; i < n4; i += stride) {
    float4 f = ((const float4*)in)[i];
    uint2 o;
    o.x = (unsigned)f2bf(f.x) | ((unsigned)f2bf(f.y) << 16);
    o.y = (unsigned)f2bf(f.z) | ((unsigned)f2bf(f.w) << 16);
    ((uint2*)out)[i] = o;
  }
}

// ---- fused: x|wq|wk|wv[|wo] f32->bf16 + RoPE tables, one launch ----
__global__ void cvt_all_kernel(const float* __restrict__ x, const float* __restrict__ wq,
                               const float* __restrict__ wk, const float* __restrict__ wv,
                               const float* __restrict__ wo, u16* __restrict__ x_bf,
                               u16* __restrict__ wqkv_bf, u16* __restrict__ wo_bf,
                               const int* __restrict__ positions, float* __restrict__ cos_t,
                               float* __restrict__ sin_t, int with_wo) {
  const int R0 = 4194304, R1 = 8388608, R2 = 9437184, R3 = 10485760, R4 = 14680064;
  const int cvt_end = with_wo ? R4 : R3;
  const int rope_units = 32768;  // 2048*64 / 4
  const int total = cvt_end + rope_units;
  const int stride = gridDim.x * blockDim.x;
  for (int i = blockIdx.x * blockDim.x + threadIdx.x; i < total; i += stride) {
    if (i < cvt_end) {
      const float* src;
      u16* dst;
      int off;
      if (i < R0)      { src = x;  dst = x_bf;               off = i; }
      else if (i < R1) { src = wq; dst = wqkv_bf;            off = i - R0; }
      else if (i < R2) { src = wk; dst = wqkv_bf + 16777216; off = i - R1; }
      else if (i < R3) { src = wv; dst = wqkv_bf + 20971520; off = i - R2; }
      else             { src = wo; dst = wo_bf;              off = i - R3; }
      float4 f = ((const float4*)src)[off];
      uint2 o;
      o.x = (unsigned)f2bf(f.x) | ((unsigned)f2bf(f.y) << 16);
      o.y = (unsigned)f2bf(f.z) | ((unsigned)f2bf(f.w) << 16);
      ((uint2*)dst)[off] = o;
    } else {
      int base = (i - cvt_end) * 4;
#pragma unroll
      for (int e = 0; e < 4; ++e) {
        int idx = base + e;
        int s = idx >> 6, j = idx & 63;
        float pos = (float)positions[s];
        float inv = expf(-(float)j * (9.210340371976184f / 64.0f));
        float sv, cv;
        sincosf(pos * inv, &sv, &cv);
        cos_t[idx] = cv;
        sin_t[idx] = sv;
      }
    }
  }
}

// ---------------- RoPE tables (fallback path) ----------------
__global__ void rope_table_kernel(const int* __restrict__ positions,
                                  float* __restrict__ cos_t, float* __restrict__ sin_t) {
  int idx = blockIdx.x * 256 + threadIdx.x;
  if (idx >= S_LEN * 64) return;
  int s = idx >> 6, j = idx & 63;
  float pos = (float)positions[s];
  float inv = expf(-(float)j * (9.210340371976184f / 64.0f));
  float sv, cv;
  sincosf(pos * inv, &sv, &cv);
  cos_t[idx] = cv;
  sin_t[idx] = sv;
}

// ---------------- 4-wave 128x256 GEMM, wave tile 64x128: C = A*B^T ----------------
// BK=32, 4 waves (2M x 2N), 72KB triple-buffered LDS, 2 blocks/CU.
// Per K-tile per wave: 12 ds_read_b128 / 32 MFMA -> MFMA-bound per SIMD
// (LDS 288 cyc < MFMA 310 cyc at 2 waves/SIMD). Cross-block asynchrony
// (2 blocks/CU) hides barrier/lgkm bubbles. stage(t+2) + vmcnt(12) keeps
// 2 tiles in flight. 4-slot swizzle: phys slot = logical ^ ((row>>1)&3)
// (inverse applied on global source) -> b128 reads at 8-lane/4-bank minimum.
// Wave (wr,wc): rows wr*64 + mf*16 (mf 0..3); cols wc*16 + nfi*32 (nfi 0..7)
// -> RoPE pairs (j, j+64) = (nfi, nfi+2) in-wave.
// EPI: 0 = f32 row-major out; 5 = fused QKV (outp = q; k = q+16777216,
//      v = k+4194304; Q/K RoPE'd [b][h][s][d], V^T [b][h][d][s])
template<int EPI>
__global__ __launch_bounds__(256, 2) void gemmp_kernel(
    const u16* __restrict__ A, const u16* __restrict__ B,
    void* __restrict__ outp, int M, int N, int K,
    const float* __restrict__ cos_t, const float* __restrict__ sin_t) {
  __shared__ u16 LDS[36864];  // A: 3 x 4096 elems at 0; B: 3 x 8192 elems at 12288
  const int t = threadIdx.x;
  const int wave = t >> 6, lane = t & 63;
  const int l15 = lane & 15, lhi = lane >> 4;
  const int wr = wave >> 1, wc = wave & 1;
  const int gx = gridDim.x;
  const int nwg = gx * gridDim.y;
  const int id = blockIdx.y * gx + blockIdx.x;
  const int swz = (id & 7) * (nwg >> 3) + (id >> 3);
  const int bm = (swz / gx) * 128, bn = (swz % gx) * 256;

  // read-side fragment offsets: row*32 + ((lhi ^ sw) << 3), sw = (l15>>1)&3
  const int sw = (l15 >> 1) & 3;
  int aoff[4], boff[8];
#pragma unroll
  for (int mf = 0; mf < 4; ++mf)
    aoff[mf] = (wr * 64 + mf * 16 + l15) * 32 + ((lhi ^ sw) << 3);
#pragma unroll
  for (int nf = 0; nf < 8; ++nf)
    boff[nf] = (wc * 16 + nf * 32 + l15) * 32 + ((lhi ^ sw) << 3);

  // staging: unit u = t + p*256; row = u>>2; phys slot = u&3;
  // source logical slot = (u&3) ^ ((u>>3)&3)  [(row>>1)&3 invariant under +64]
  const int r0 = t >> 2;
  const int cs = (((t & 3) ^ ((t >> 3) & 3)) << 3);

  const f32x4 fz = {0.f, 0.f, 0.f, 0.f};
  f32x4 acc[4][8];
#pragma unroll
  for (int mf = 0; mf < 4; ++mf)
#pragma unroll
    for (int nf = 0; nf < 8; ++nf) acc[mf][nf] = fz;

  auto stageA = [&](int tile, int buf) {  // 2 gloads (128 x 32)
    const size_t kb = (size_t)tile * 32;
    const u16* s0 = A + (size_t)(bm + r0) * K + kb + cs;
    u16* d = &LDS[buf * 4096 + (wave << 9)];
    gload16(s0, d);
    gload16(s0 + (size_t)64 * K, d + 2048);
  };
  auto stageB = [&](int tile, int buf) {  // 4 gloads (256 x 32)
    const size_t kb = (size_t)tile * 32;
    const u16* s0 = B + (size_t)(bn + r0) * K + kb + cs;
    u16* d = &LDS[12288 + buf * 8192 + (wave << 9)];
    gload16(s0, d);
    gload16(s0 + (size_t)64 * K, d + 2048);
    gload16(s0 + (size_t)128 * K, d + 4096);
    gload16(s0 + (size_t)192 * K, d + 6144);
  };

  const int nt = K >> 5;
  // prologue: stage tiles 0,1 (6 loads each -> 12 outstanding)
  stageA(0, 0); stageB(0, 0);
  stageA(1, 1); stageB(1, 1);

  int cur = 0, nx2 = 2;
  s16x8 afr[4], bfr[8];
  for (int tt = 0; tt < nt; ++tt) {
    if (tt + 2 < nt) {
      stageA(tt + 2, nx2); stageB(tt + 2, nx2);
      asm volatile("s_waitcnt vmcnt(12)" ::: "memory");  // drain tile tt
    } else if (tt + 1 < nt) {
      asm volatile("s_waitcnt vmcnt(6)" ::: "memory");
    } else {
      asm volatile("s_waitcnt vmcnt(0)" ::: "memory");
    }
    __builtin_amdgcn_sched_barrier(0);
    __builtin_amdgcn_s_barrier();  // buf cur ready for all waves
    __builtin_amdgcn_sched_barrier(0);

    const int ab = cur * 4096;
    const int bb = 12288 + cur * 8192;
#pragma unroll
    for (int mf = 0; mf < 4; ++mf) afr[mf] = *(const s16x8*)&LDS[ab + aoff[mf]];
#pragma unroll
    for (int nf = 0; nf < 8; ++nf) bfr[nf] = *(const s16x8*)&LDS[bb + boff[nf]];
    asm volatile("s_waitcnt lgkmcnt(0)" ::: "memory");
    __builtin_amdgcn_sched_barrier(0);
    __builtin_amdgcn_s_barrier();  // all waves' reads done -> cur may be restaged

    __builtin_amdgcn_s_setprio(1);
#pragma unroll
    for (int mf = 0; mf < 4; ++mf)
#pragma unroll
      for (int nf = 0; nf < 8; ++nf)
        acc[mf][nf] = __builtin_amdgcn_mfma_f32_16x16x32_bf16(afr[mf], bfr[nf], acc[mf][nf], 0, 0, 0);
    __builtin_amdgcn_s_setprio(0);

    cur = (cur == 2) ? 0 : cur + 1;
    nx2 = (nx2 == 2) ? 0 : nx2 + 1;
  }

  // ---- epilogue: row = bm + wr*64 + mf*16 + lhi*4 + i;
  //      col = bn + wc*16 + nfi*32 + l15
  if constexpr (EPI == 0) {
    float* C = (float*)outp;
#pragma unroll
    for (int mf = 0; mf < 4; ++mf) {
      int rb = bm + wr * 64 + mf * 16 + lhi * 4;
#pragma unroll
      for (int nfi = 0; nfi < 8; ++nfi) {
        int col = bn + wc * 16 + nfi * 32 + l15;
#pragma unroll
        for (int i = 0; i < 4; ++i) C[(size_t)(rb + i) * N + col] = acc[mf][nfi][i];
      }
    }
  } else {  // EPI == 5: fused QKV
    u16* qp = (u16*)outp;
    u16* kp = qp + 16777216;  // 2*32*2048*128
    u16* vp = kp + 4194304;   // 2*8*2048*128
    if (bn < 5120) {
      const bool isQ = bn < 4096;
      u16* O = isQ ? qp : kp;
      const int hb = isQ ? (bn >> 7) : ((bn - 4096) >> 7);
      const int Hh = isQ ? NH_Q : NKV_H;
#pragma unroll
      for (int mf = 0; mf < 4; ++mf) {
        int rb = bm + wr * 64 + mf * 16 + lhi * 4;
#pragma unroll
        for (int p = 0; p < 2; ++p) {  // head within 256-col block
          int head = hb + p;
#pragma unroll
          for (int q01 = 0; q01 < 2; ++q01) {
            int j = wc * 16 + q01 * 32 + l15;  // 0..63
#pragma unroll
            for (int i = 0; i < 4; ++i) {
              int m = rb + i;
              int b = m >> 11, srw = m & 2047;
              float c = cos_t[srw * 64 + j];
              float s = sin_t[srw * 64 + j];
              float x0 = acc[mf][p * 4 + q01][i];
              float x1 = acc[mf][p * 4 + q01 + 2][i];
              size_t base = ((size_t)(b * Hh + head) * S_LEN + srw) * DHEAD;
              O[base + j] = f2bf(x0 * c - x1 * s);
              O[base + j + 64] = f2bf(x0 * s + x1 * c);
            }
          }
        }
      }
    } else {  // V transposed [b][h][d][s]
#pragma unroll
      for (int mf = 0; mf < 4; ++mf) {
        int rb = bm + wr * 64 + mf * 16 + lhi * 4;
#pragma unroll
        for (int nfi = 0; nfi < 8; ++nfi) {
          int colrel = bn - 5120 + wc * 16 + nfi * 32 + l15;
          int head = colrel >> 7, d = colrel & 127;
#pragma unroll
          for (int i = 0; i < 4; ++i) {
            int m = rb + i;
            int b = m >> 11, srw = m & 2047;
            vp[((size_t)(b * NKV_H + head) * DHEAD + d) * S_LEN + srw] = f2bf(acc[mf][nfi][i]);
          }
        }
      }
    }
  }
}

// ---------------- reg-staged GEMM (fallback path only) ----------------
template<int EPI, bool ABF16, bool BBF16>
__global__ __launch_bounds__(256) void gemm_kernel(
    const void* __restrict__ Aptr, const void* __restrict__ Bptr,
    void* __restrict__ outp, void* __restrict__ outp2, int M, int N, int K,
    const float* __restrict__ cos_t, const float* __restrict__ sin_t, int Hh) {
  __shared__ u16 As[128][72];
  __shared__ u16 Bs[128][72];
  const int t = threadIdx.x;
  const int wave = t >> 6, lane = t & 63;
  const int l15 = lane & 15, lhi = lane >> 4;
  const int gx = gridDim.x;
  const int nwg = gx * gridDim.y;
  const int id = blockIdx.y * gx + blockIdx.x;
  const int swz = (id & 7) * (nwg >> 3) + (id >> 3);
  const int bm = (swz / gx) * 128, bn = (swz % gx) * 128;

  const f32x4 fz = {0.f, 0.f, 0.f, 0.f};
  f32x4 acc[2][8];
#pragma unroll
  for (int a0 = 0; a0 < 2; ++a0)
#pragma unroll
    for (int b0 = 0; b0 < 8; ++b0) acc[a0][b0] = fz;

  for (int kt = 0; kt < K; kt += 64) {
    __syncthreads();
    if (ABF16) {
      const u16* A = (const u16*)Aptr;
#pragma unroll
      for (int p = 0; p < 4; ++p) {
        int row = p * 32 + (t >> 3), kc = (t & 7) * 8;
        *(s16x8*)&As[row][kc] = *(const s16x8*)(A + (size_t)(bm + row) * K + kt + kc);
      }
    } else {
      const float* A = (const float*)Aptr;
#pragma unroll
      for (int p = 0; p < 8; ++p) {
        int row = p * 16 + (t >> 4), kc = (t & 15) * 4;
        float4 f = *(const float4*)(A + (size_t)(bm + row) * K + kt + kc);
        unsigned* dst = (unsigned*)&As[row][kc];
        dst[0] = (unsigned)f2bf(f.x) | ((unsigned)f2bf(f.y) << 16);
        dst[1] = (unsigned)f2bf(f.z) | ((unsigned)f2bf(f.w) << 16);
      }
    }
    if (BBF16) {
      const u16* Bw = (const u16*)Bptr;
#pragma unroll
      for (int p = 0; p < 4; ++p) {
        int row = p * 32 + (t >> 3), kc = (t & 7) * 8;
        *(s16x8*)&Bs[row][kc] = *(const s16x8*)(Bw + (size_t)(bn + row) * K + kt + kc);
      }
    } else {
      const float* Bw = (const float*)Bptr;
#pragma unroll
      for (int p = 0; p < 8; ++p) {
        int row = p * 16 + (t >> 4), kc = (t & 15) * 4;
        float4 f = *(const float4*)(Bw + (size_t)(bn + row) * K + kt + kc);
        unsigned* dst = (unsigned*)&Bs[row][kc];
        dst[0] = (unsigned)f2bf(f.x) | ((unsigned)f2bf(f.y) << 16);
        dst[1] = (unsigned)f2bf(f.z) | ((unsigned)f2bf(f.w) << 16);
      }
    }
    __syncthreads();
#pragma unroll
    for (int ks = 0; ks < 2; ++ks) {
      s16x8 bfr[8];
#pragma unroll
      for (int nf = 0; nf < 8; ++nf)
        bfr[nf] = *(const s16x8*)&Bs[nf * 16 + l15][ks * 32 + lhi * 8];
#pragma unroll
      for (int mf = 0; mf < 2; ++mf) {
        s16x8 a = *(const s16x8*)&As[wave * 32 + mf * 16 + l15][ks * 32 + lhi * 8];
#pragma unroll
        for (int nf = 0; nf < 8; ++nf)
          acc[mf][nf] = __builtin_amdgcn_mfma_f32_16x16x32_bf16(a, bfr[nf], acc[mf][nf], 0, 0, 0);
      }
    }
  }

  if (EPI == 0) {
    float* C = (float*)outp;
#pragma unroll
    for (int mf = 0; mf < 2; ++mf)
#pragma unroll
      for (int nf = 0; nf < 8; ++nf) {
        int col = bn + nf * 16 + l15;
        int rb = bm + wave * 32 + mf * 16 + lhi * 4;
#pragma unroll
        for (int i = 0; i < 4; ++i) C[(size_t)(rb + i) * N + col] = acc[mf][nf][i];
      }
  } else if (EPI == 2) {
    u16* O = (u16*)outp;
    int h = bn >> 7;
#pragma unroll
    for (int mf = 0; mf < 2; ++mf)
#pragma unroll
      for (int nf = 0; nf < 4; ++nf) {
        int j = nf * 16 + l15;
        int rb = bm + wave * 32 + mf * 16 + lhi * 4;
#pragma unroll
        for (int i = 0; i < 4; ++i) {
          int m = rb + i;
          int b = m >> 11, srow = m & 2047;
          float c = cos_t[srow * 64 + j];
          float s = sin_t[srow * 64 + j];
          float x0 = acc[mf][nf][i];
          float x1 = acc[mf][nf + 4][i];
          size_t base = ((size_t)(b * Hh + h) * S_LEN + srow) * DHEAD;
          O[base + j] = f2bf(x0 * c - x1 * s);
          O[base + j + 64] = f2bf(x0 * s + x1 * c);
        }
      }
  } else {  // EPI == 4: bf16 transposed [b][h][d][s]
    u16* O = (u16*)outp;
#pragma unroll
    for (int mf = 0; mf < 2; ++mf)
#pragma unroll
      for (int nf = 0; nf < 8; ++nf) {
        int col = bn + nf * 16 + l15;
        int h = col >> 7, d = col & 127;
        int rb = bm + wave * 32 + mf * 16 + lhi * 4;
#pragma unroll
        for (int i = 0; i < 4; ++i) {
          int m = rb + i;
          int b = m >> 11, srow = m & 2047;
          O[((size_t)(b * Hh + h) * DHEAD + d) * S_LEN + srow] = f2bf(acc[mf][nf][i]);
        }
      }
  }
}

// ---------------- Flash attention (causal, GQA) ----------------
#define KIDX(r, c) (((r) * 128 + (c)) ^ (((r) & 7) << 3))
#define VIDX(d, kv) (((d) * 64 + (kv)) ^ (((d) & 7) << 3))
__global__ __launch_bounds__(512) void attn_kernel(
    const u16* __restrict__ q, const u16* __restrict__ k, const u16* __restrict__ vt,
    u16* __restrict__ ctx) {
  __shared__ u16 Ks[64 * 128];
  __shared__ u16 Vts[128 * 64];

  const int t = threadIdx.x;
  const int wave = t >> 6, lane = t & 63;
  const int l15 = lane & 15, lhi = lane >> 4;
  const int pi = blockIdx.x, h = blockIdx.y, b = blockIdx.z;
  const int kvh = h >> 2;
  const int qsub[2] = {pi, 15 - pi};
  const int ntiles = 32 - 2 * pi;

  const u16* qb = q + ((size_t)(b * NH_Q + h)) * S_LEN * DHEAD;
  const u16* kb = k + ((size_t)(b * NKV_H + kvh)) * S_LEN * DHEAD;
  const u16* vtb = vt + ((size_t)(b * NKV_H + kvh)) * DHEAD * S_LEN;

  s16x8 qf[2][4];
#pragma unroll
  for (int s = 0; s < 2; ++s)
#pragma unroll
    for (int ks = 0; ks < 4; ++ks)
      qf[s][ks] = *(const s16x8*)(qb + (size_t)(qsub[s] * 128 + wave * 16 + l15) * DHEAD +
                                  ks * 32 + lhi * 8);

  const f32x4 fz = {0.f, 0.f, 0.f, 0.f};
  f32x4 acc[2][8];
#pragma unroll
  for (int s = 0; s < 2; ++s)
#pragma unroll
    for (int i = 0; i < 8; ++i) acc[s][i] = fz;
  float mrow[2] = {-INFINITY, -INFINITY};
  float lsum[2] = {0.f, 0.f};

  const float scale = 0.08838834764831845f;

  const int sl0 = l15 | (((2 * lhi) & 3) << 4);
  const int sl1 = sl0 | 16;
  const bool hisel = (lhi & 2) != 0;

  const int krow = t >> 3, kd0 = (t & 7) * 16;
  const int vrow = t >> 2, vk0 = (t & 3) * 16;
  s16x8 kr0, kr1, vr0, vr1;
  {
    const u16* p = kb + (size_t)krow * DHEAD + kd0;
    kr0 = *(const s16x8*)p;
    kr1 = *(const s16x8*)(p + 8);
    const u16* pv = vtb + (size_t)vrow * S_LEN + vk0;
    vr0 = *(const s16x8*)pv;
    vr1 = *(const s16x8*)(pv + 8);
  }

  for (int tt = 0; tt < ntiles; ++tt) {
    __syncthreads();
    *(s16x8*)&Ks[KIDX(krow, kd0)] = kr0;
    *(s16x8*)&Ks[KIDX(krow, kd0 + 8)] = kr1;
    *(s16x8*)&Vts[VIDX(vrow, vk0)] = vr0;
    *(s16x8*)&Vts[VIDX(vrow, vk0 + 8)] = vr1;
    __syncthreads();
    if (tt + 1 < ntiles) {
      const u16* p = kb + (size_t)((tt + 1) * 64 + krow) * DHEAD + kd0;
      kr0 = *(const s16x8*)p;
      kr1 = *(const s16x8*)(p + 8);
      const u16* pv = vtb + (size_t)vrow * S_LEN + (tt + 1) * 64 + vk0;
      vr0 = *(const s16x8*)pv;
      vr1 = *(const s16x8*)(pv + 8);
    }

    const int kc_base = tt * 64;
#pragma unroll
    for (int s = 0; s < 2; ++s) {
      const int wmin = qsub[s] * 128 + wave * 16;
      if (kc_base > wmin + 15) continue;
      f32x4 sacc[4];
#pragma unroll
      for (int i = 0; i < 4; ++i) sacc[i] = fz;
      __builtin_amdgcn_s_setprio(1);
#pragma unroll
      for (int ks = 0; ks < 4; ++ks) {
#pragma unroll
        for (int nf = 0; nf < 4; ++nf) {
          s16x8 kf = *(const s16x8*)&Ks[KIDX(nf * 16 + l15, ks * 32 + lhi * 8)];
          sacc[nf] = __builtin_amdgcn_mfma_f32_16x16x32_bf16(kf, qf[s][ks], sacc[nf], 0, 0, 0);
        }
      }
      __builtin_amdgcn_s_setprio(0);

      const int qg = wmin + l15;
      float pmax = -INFINITY;
      if (kc_base + 63 > wmin) {
#pragma unroll
        for (int nf = 0; nf < 4; ++nf)
#pragma unroll
          for (int i = 0; i < 4; ++i) {
            int kv = kc_base + nf * 16 + lhi * 4 + i;
            float sv = sacc[nf][i] * scale;
            sv = (kv <= qg) ? sv : -INFINITY;
            sacc[nf][i] = sv;
            pmax = fmaxf(pmax, sv);
          }
      } else {
#pragma unroll
        for (int nf = 0; nf < 4; ++nf)
#pragma unroll
          for (int i = 0; i < 4; ++i) {
            float sv = sacc[nf][i] * scale;
            sacc[nf][i] = sv;
            pmax = fmaxf(pmax, sv);
          }
      }
      pmax = fmaxf(pmax, __shfl_xor(pmax, 16, 64));
      pmax = fmaxf(pmax, __shfl_xor(pmax, 32, 64));

      if (!__all(pmax <= mrow[s] + 8.0f)) {
        float mnew = fmaxf(mrow[s], pmax);
        float alpha = __expf(mrow[s] - mnew);
        mrow[s] = mnew;
        lsum[s] *= alpha;
#pragma unroll
        for (int i = 0; i < 4; ++i) {
          float al = __shfl(alpha, (lane & 48) | (lhi * 4 + i), 64);
#pragma unroll
          for (int df = 0; df < 8; ++df) acc[s][df][i] *= al;
        }
      }

      float rsum = 0.f;
      unsigned pk[4][2];
#pragma unroll
      for (int nf = 0; nf < 4; ++nf) {
        float p0 = __expf(sacc[nf][0] - mrow[s]);
        float p1 = __expf(sacc[nf][1] - mrow[s]);
        float p2 = __expf(sacc[nf][2] - mrow[s]);
        float p3 = __expf(sacc[nf][3] - mrow[s]);
        rsum += (p0 + p1) + (p2 + p3);
        pk[nf][0] = (unsigned)f2bf(p0) | ((unsigned)f2bf(p1) << 16);
        pk[nf][1] = (unsigned)f2bf(p2) | ((unsigned)f2bf(p3) << 16);
      }
      rsum += __shfl_xor(rsum, 16, 64);
      rsum += __shfl_xor(rsum, 32, 64);
      lsum[s] += rsum;

      s16x8 pa[2];
#pragma unroll
      for (int ph = 0; ph < 2; ++ph) {
        unsigned lo0 = __shfl((int)pk[2 * ph][0], sl0, 64);
        unsigned hi0 = __shfl((int)pk[2 * ph + 1][0], sl0, 64);
        unsigned lo1 = __shfl((int)pk[2 * ph][1], sl0, 64);
        unsigned hi1 = __shfl((int)pk[2 * ph + 1][1], sl0, 64);
        unsigned lo2 = __shfl((int)pk[2 * ph][0], sl1, 64);
        unsigned hi2 = __shfl((int)pk[2 * ph + 1][0], sl1, 64);
        unsigned lo3 = __shfl((int)pk[2 * ph][1], sl1, 64);
        unsigned hi3 = __shfl((int)pk[2 * ph + 1][1], sl1, 64);
        u32x4 w;
        w[0] = hisel ? hi0 : lo0;
        w[1] = hisel ? hi1 : lo1;
        w[2] = hisel ? hi2 : lo2;
        w[3] = hisel ? hi3 : lo3;
        pa[ph] = __builtin_bit_cast(s16x8, w);
      }

      __builtin_amdgcn_s_setprio(1);
#pragma unroll
      for (int ph = 0; ph < 2; ++ph) {
#pragma unroll
        for (int df = 0; df < 8; ++df) {
          s16x8 bb = *(const s16x8*)&Vts[VIDX(df * 16 + l15, ph * 32 + lhi * 8)];
          acc[s][df] = __builtin_amdgcn_mfma_f32_16x16x32_bf16(pa[ph], bb, acc[s][df], 0, 0, 0);
        }
      }
      __builtin_amdgcn_s_setprio(0);
    }
  }

#pragma unroll
  for (int s = 0; s < 2; ++s) {
    float rl = 1.0f / lsum[s];
#pragma unroll
    for (int i = 0; i < 4; ++i) {
      float rli = __shfl(rl, (lane & 48) | (lhi * 4 + i), 64);
      int m = b * S_LEN + qsub[s] * 128 + wave * 16 + lhi * 4 + i;
#pragma unroll
      for (int df = 0; df < 8; ++df) {
        int col = h * DHEAD + df * 16 + l15;
        ctx[(size_t)m * (NH_Q * DHEAD) + col] = f2bf(acc[s][df][i] * rli);
      }
    }
  }
}

extern "C" void kernel_launch(void* const* d_in, const int* in_sizes, int n_in,
                              void* d_out, int out_size, void* d_ws, size_t ws_size,
                              hipStream_t stream) {
  const float* x = (const float*)d_in[0];
  const int* positions = (const int*)d_in[1];
  const float* wq = (const float*)d_in[2];
  const float* wk = (const float*)d_in[3];
  const float* wv = (const float*)d_in[4];
  const float* wo = (const float*)d_in[5];
  float* out = (float*)d_out;

  char* ws = (char*)d_ws;
  const size_t MB1 = 1048576;
  const size_t SZ_X = 33554432;     // 2*2048*4096 bf16
  const size_t SZ_WQKV = 50331648;  // 6144*4096 bf16
  const size_t SZ_WO = 33554432;    // 4096*4096 bf16
  const size_t SZ_Q = 33554432;     // q bf16
  const size_t SZ_WK = 8388608;     // k or v bf16
  const size_t NEED_FULL = MB1 + SZ_X + SZ_WQKV + SZ_Q + 2 * SZ_WK;  // 129 MB
  const size_t NEED_WO = NEED_FULL + SZ_WO;                          // 161 MB

  float* cos_t = (float*)ws;
  float* sin_t = (float*)(ws + MB1 / 2);

  if (ws_size >= NEED_WO) {
    char* p = ws + MB1;
    u16* x_bf = (u16*)p;    p += SZ_X;     // later reused as ctx
    u16* wqkv_bf = (u16*)p; p += SZ_WQKV;  // wq|wk|wv stacked
    u16* wo_bf = (u16*)p;   p += SZ_WO;
    u16* q_ws = (u16*)p;    p += SZ_Q;     // q | k | v contiguous
    u16* k_ws = (u16*)p;    p += SZ_WK;
    u16* v_ws = (u16*)p;    p += SZ_WK;
    u16* ctx_ws = x_bf;

    cvt_all_kernel<<<2048, 256, 0, stream>>>(x, wq, wk, wv, wo, x_bf, wqkv_bf, wo_bf,
                                             positions, cos_t, sin_t, 1);
    // fused QKV: 128x256 tiles, grid (24,32) = 768 blocks = 3/CU count-balanced
    gemmp_kernel<5><<<dim3(24, 32), 256, 0, stream>>>(
        x_bf, wqkv_bf, q_ws, 4096, 6144, 4096, cos_t, sin_t);
    attn_kernel<<<dim3(8, 32, 2), 512, 0, stream>>>(q_ws, k_ws, v_ws, ctx_ws);
    // out-proj: 128x256 tiles, grid (16,32) = 512 blocks = 2/CU exact
    gemmp_kernel<0><<<dim3(16, 32), 256, 0, stream>>>(
        ctx_ws, wo_bf, out, 4096, 4096, 4096, nullptr, nullptr);
  } else if (ws_size >= NEED_FULL) {
    char* p = ws + MB1;
    u16* x_bf = (u16*)p;    p += SZ_X;
    u16* wqkv_bf = (u16*)p; p += SZ_WQKV;
    u16* q_ws = (u16*)p;    p += SZ_Q;
    u16* k_ws = (u16*)p;    p += SZ_WK;
    u16* v_ws = (u16*)p;    p += SZ_WK;
    u16* ctx_ws = x_bf;

    cvt_all_kernel<<<2048, 256, 0, stream>>>(x, wq, wk, wv, nullptr, x_bf, wqkv_bf, nullptr,
                                             positions, cos_t, sin_t, 0);
    gemmp_kernel<5><<<dim3(24, 32), 256, 0, stream>>>(
        x_bf, wqkv_bf, q_ws, 4096, 6144, 4096, cos_t, sin_t);
    cvt_kernel<<<2048, 256, 0, stream>>>(wo, wqkv_bf, 4194304);  // wqkv_bf now = wo_bf
    attn_kernel<<<dim3(8, 32, 2), 512, 0, stream>>>(q_ws, k_ws, v_ws, ctx_ws);
    gemmp_kernel<0><<<dim3(16, 32), 256, 0, stream>>>(
        ctx_ws, wqkv_bf, out, 4096, 4096, 4096, nullptr, nullptr);
  } else {
    u16* q_ws = (u16*)(ws + MB1);
    u16* k_ws = (u16*)(ws + MB1 + SZ_Q);
    u16* v_ws = (u16*)(ws + MB1 + SZ_Q + SZ_WK);
    u16* ctx_ws = (u16*)(ws + MB1 + SZ_Q + 2 * SZ_WK);

    rope_table_kernel<<<512, 256, 0, stream>>>(positions, cos_t, sin_t);
    gemm_kernel<2, false, false><<<dim3(32, 32), 256, 0, stream>>>(
        x, wq, q_ws, nullptr, 4096, 4096, 4096, cos_t, sin_t, NH_Q);
    gemm_kernel<2, false, false><<<dim3(8, 32), 256, 0, stream>>>(
        x, wk, k_ws, nullptr, 4096, 1024, 4096, cos_t, sin_t, NKV_H);
    gemm_kernel<4, false, false><<<dim3(8, 32), 256, 0, stream>>>(
        x, wv, v_ws, nullptr, 4096, 1024, 4096, nullptr, nullptr, NKV_H);
    attn_kernel<<<dim3(8, 32, 2), 512, 0, stream>>>(q_ws, k_ws, v_ws, ctx_ws);
    gemm_kernel<0, true, false><<<dim3(32, 32), 256, 0, stream>>>(
        ctx_ws, wo, out, nullptr, 4096, 4096, 4096, nullptr, nullptr, 0);
  }
}

// Round 14
// 522.456 us; speedup vs baseline: 1.0869x; 1.0869x over previous
//
#include <hip/hip_runtime.h>
#include <math.h>

typedef short s16x8 __attribute__((ext_vector_type(8)));
typedef float f32x4 __attribute__((ext_vector_type(4)));
typedef unsigned u32x4 __attribute__((ext_vector_type(4)));
typedef unsigned short u16;

#define S_LEN 2048
#define HID_DIM 4096
#define NH_Q 32
#define NKV_H 8
#define DHEAD 128

__device__ __forceinline__ u16 f2bf(float f) {
  unsigned u = __builtin_bit_cast(unsigned, f);
  u += 0x7fffu + ((u >> 16) & 1u);
  return (u16)(u >> 16);
}

// async global -> LDS, 16B per lane; lds base wave-uniform, lane*16 auto-offset
__device__ __forceinline__ void gload16(const u16* g, u16* l) {
  __builtin_amdgcn_global_load_lds(
      (const __attribute__((address_space(1))) void*)g,
      (__attribute__((address_space(3))) void*)l, 16, 0, 0);
}

// ---------------- f32 -> bf16 bulk convert (single region) ----------------
__global__ void cvt_kernel(const float* __restrict__ in, u16* __restrict__ out, int n4) {
  int stride = gridDim.x * blockDim.x;
  for (int i = blockIdx.x * blockDim.x + threadIdx.x; i < n4; i += stride) {
    float4 f = ((const float4*)in)[i];
    uint2 o;
    o.x = (unsigned)f2bf(f.x) | ((unsigned)f2bf(f.y) << 16);
    o.y = (unsigned)f2bf(f.z) | ((unsigned)f2bf(f.w) << 16);
    ((uint2*)out)[i] = o;
  }
}

// ---- fused: x|wq|wk|wv[|wo] f32->bf16 + RoPE tables, one launch ----
__global__ void cvt_all_kernel(const float* __restrict__ x, const float* __restrict__ wq,
                               const float* __restrict__ wk, const float* __restrict__ wv,
                               const float* __restrict__ wo, u16* __restrict__ x_bf,
                               u16* __restrict__ wqkv_bf, u16* __restrict__ wo_bf,
                               const int* __restrict__ positions, float* __restrict__ cos_t,
                               float* __restrict__ sin_t, int with_wo) {
  const int R0 = 4194304, R1 = 8388608, R2 = 9437184, R3 = 10485760, R4 = 14680064;
  const int cvt_end = with_wo ? R4 : R3;
  const int rope_units = 32768;  // 2048*64 / 4
  const int total = cvt_end + rope_units;
  const int stride = gridDim.x * blockDim.x;
  for (int i = blockIdx.x * blockDim.x + threadIdx.x; i < total; i += stride) {
    if (i < cvt_end) {
      const float* src;
      u16* dst;
      int off;
      if (i < R0)      { src = x;  dst = x_bf;               off = i; }
      else if (i < R1) { src = wq; dst = wqkv_bf;            off = i - R0; }
      else if (i < R2) { src = wk; dst = wqkv_bf + 16777216; off = i - R1; }
      else if (i < R3) { src = wv; dst = wqkv_bf + 20971520; off = i - R2; }
      else             { src = wo; dst = wo_bf;              off = i - R3; }
      float4 f = ((const float4*)src)[off];
      uint2 o;
      o.x = (unsigned)f2bf(f.x) | ((unsigned)f2bf(f.y) << 16);
      o.y = (unsigned)f2bf(f.z) | ((unsigned)f2bf(f.w) << 16);
      ((uint2*)dst)[off] = o;
    } else {
      int base = (i - cvt_end) * 4;
#pragma unroll
      for (int e = 0; e < 4; ++e) {
        int idx = base + e;
        int s = idx >> 6, j = idx & 63;
        float pos = (float)positions[s];
        float inv = expf(-(float)j * (9.210340371976184f / 64.0f));
        float sv, cv;
        sincosf(pos * inv, &sv, &cv);
        cos_t[idx] = cv;
        sin_t[idx] = sv;
      }
    }
  }
}

// ---------------- RoPE tables (fallback path) ----------------
__global__ void rope_table_kernel(const int* __restrict__ positions,
                                  float* __restrict__ cos_t, float* __restrict__ sin_t) {
  int idx = blockIdx.x * 256 + threadIdx.x;
  if (idx >= S_LEN * 64) return;
  int s = idx >> 6, j = idx & 63;
  float pos = (float)positions[s];
  float inv = expf(-(float)j * (9.210340371976184f / 64.0f));
  float sv, cv;
  sincosf(pos * inv, &sv, &cv);
  cos_t[idx] = cv;
  sin_t[idx] = sv;
}

// ---------------- pipelined 128x256 GEMM (R12 engine): C = A[M][K]*B[N][K]^T ----
// BK=64, 8 waves (2M x 4N), 144KB triple-buffered LDS, 1 block/CU.
// READ-AHEAD pipeline: all 16 ds_reads of tile t+1 issued right after the
// single per-tile barrier, overlapping tile t's second MFMA cluster; double
// register sets. Counted vmcnt(6) keeps tile t+2's 6 loads in flight.
// EPI: 5 = fused QKV (outp = q; k = q+16777216, v = k+4194304;
//      Q/K RoPE'd [b][h][s][d], V^T [b][h][d][s])
template<int EPI>
__global__ __launch_bounds__(512, 2) void gemmp_kernel(
    const u16* __restrict__ A, const u16* __restrict__ B,
    void* __restrict__ outp, int M, int N, int K,
    const float* __restrict__ cos_t, const float* __restrict__ sin_t) {
  __shared__ u16 LDS[73728];  // A 3 x 8192 elems at 0; B 3 x 16384 at 24576
  const int t = threadIdx.x;
  const int wave = t >> 6, lane = t & 63;
  const int l15 = lane & 15, lhi = lane >> 4;
  const int wr = wave >> 2, wc = wave & 3;
  const int gx = gridDim.x;
  const int nwg = gx * gridDim.y;
  const int id = blockIdx.y * gx + blockIdx.x;
  const int swz = (id & 7) * (nwg >> 3) + (id >> 3);
  const int bm = (swz / gx) * 128, bn = (swz % gx) * 256;

  const int sw = l15 & 7;
  int aoff[4][2], boff[2][2];
#pragma unroll
  for (int q = 0; q < 4; ++q)
#pragma unroll
    for (int ks = 0; ks < 2; ++ks)
      aoff[q][ks] = wr * 4096 + (q * 16 + l15) * 64 + (((ks << 2) + lhi) ^ sw) * 8;
#pragma unroll
  for (int f = 0; f < 2; ++f)
#pragma unroll
    for (int ks = 0; ks < 2; ++ks)
      boff[f][ks] = (f * 64 + wc * 16 + l15) * 64 + (((ks << 2) + lhi) ^ sw) * 8;

  const int lr1 = t >> 3;                     // 0..63
  const int cs1 = ((t & 7) ^ (lr1 & 7)) * 8;  // inverse swizzle
  const int ldsw = wave * 512;

  const f32x4 fz = {0.f, 0.f, 0.f, 0.f};
  f32x4 acc[4][4];
#pragma unroll
  for (int mf = 0; mf < 4; ++mf)
#pragma unroll
    for (int nf = 0; nf < 4; ++nf) acc[mf][nf] = fz;

  auto stageA = [&](int tile, int buf) {
    const size_t kb = (size_t)tile * 64;
    gload16(A + (size_t)(bm + lr1) * K + kb + cs1, &LDS[buf * 8192 + ldsw]);
    gload16(A + (size_t)(bm + 64 + lr1) * K + kb + cs1, &LDS[buf * 8192 + 4096 + ldsw]);
  };
  auto stageB = [&](int tile, int h, int buf) {
    const size_t kb = (size_t)tile * 64;
    gload16(B + (size_t)(bn + h * 128 + lr1) * K + kb + cs1,
            &LDS[24576 + buf * 16384 + h * 8192 + ldsw]);
    gload16(B + (size_t)(bn + h * 128 + 64 + lr1) * K + kb + cs1,
            &LDS[24576 + buf * 16384 + h * 8192 + 4096 + ldsw]);
  };

  s16x8 afr0[4][2], afr1[4][2];
  s16x8 bfr00[2][2], bfr01[2][2];
  s16x8 bfr10[2][2], bfr11[2][2];

#define READ_TILE(SET, BUF)                                                \
  do {                                                                     \
    const int _b = (BUF);                                                  \
    const int _ba = _b * 8192;                                             \
    _Pragma("unroll") for (int q = 0; q < 4; ++q)                          \
      _Pragma("unroll") for (int ks = 0; ks < 2; ++ks)                     \
        afr##SET[q][ks] = *(const s16x8*)&LDS[_ba + aoff[q][ks]];          \
    const int _b0 = 24576 + _b * 16384;                                    \
    _Pragma("unroll") for (int f = 0; f < 2; ++f)                          \
      _Pragma("unroll") for (int ks = 0; ks < 2; ++ks)                     \
        bfr0##SET[f][ks] = *(const s16x8*)&LDS[_b0 + boff[f][ks]];         \
    const int _b1 = _b0 + 8192;                                            \
    _Pragma("unroll") for (int f = 0; f < 2; ++f)                          \
      _Pragma("unroll") for (int ks = 0; ks < 2; ++ks)                     \
        bfr1##SET[f][ks] = *(const s16x8*)&LDS[_b1 + boff[f][ks]];         \
  } while (0)

#define MFMA_HALF(SET, NFH, BH)                                            \
  do {                                                                     \
    __builtin_amdgcn_s_setprio(1);                                         \
    _Pragma("unroll") for (int q = 0; q < 4; ++q)                          \
      _Pragma("unroll") for (int f = 0; f < 2; ++f)                        \
        _Pragma("unroll") for (int ks = 0; ks < 2; ++ks)                   \
          acc[q][(NFH)*2 + f] = __builtin_amdgcn_mfma_f32_16x16x32_bf16(   \
              afr##SET[q][ks], bfr##BH##SET[f][ks], acc[q][(NFH)*2 + f],   \
              0, 0, 0);                                                    \
    __builtin_amdgcn_s_setprio(0);                                         \
  } while (0)

#define TILE_BODY(SET, OSET, TT)                                           \
  do {                                                                     \
    const int _tt = (TT);                                                  \
    const bool _s2 = _tt + 2 < nt;                                         \
    if (_s2) { stageA(_tt + 2, nx2); stageB(_tt + 2, 0, nx2); }            \
    asm volatile("s_waitcnt lgkmcnt(0)" ::: "memory");                     \
    __builtin_amdgcn_sched_barrier(0);                                     \
    MFMA_HALF(SET, 0, 0);                                                  \
    if (_s2) stageB(_tt + 2, 1, nx2);                                      \
    if (_tt + 1 < nt) {                                                    \
      if (_s2) { asm volatile("s_waitcnt vmcnt(6)" ::: "memory"); }        \
      else     { asm volatile("s_waitcnt vmcnt(0)" ::: "memory"); }        \
      __builtin_amdgcn_sched_barrier(0);                                   \
      __builtin_amdgcn_s_barrier();                                        \
      __builtin_amdgcn_sched_barrier(0);                                   \
      READ_TILE(OSET, nxt1);                                               \
    }                                                                      \
    MFMA_HALF(SET, 1, 1);                                                  \
    nxt1 = nx2;                                                            \
    nx2 = (nx2 == 2) ? 0 : nx2 + 1;                                        \
  } while (0)

  const int nt = K >> 6;
  stageA(0, 0); stageB(0, 0, 0); stageB(0, 1, 0);
  stageA(1, 1); stageB(1, 0, 1); stageB(1, 1, 1);
  asm volatile("s_waitcnt vmcnt(6)" ::: "memory");
  __builtin_amdgcn_sched_barrier(0);
  __builtin_amdgcn_s_barrier();
  __builtin_amdgcn_sched_barrier(0);
  READ_TILE(0, 0);

  int nxt1 = 1, nx2 = 2;
  for (int tt = 0; tt < nt; tt += 2) {
    TILE_BODY(0, 1, tt);
    TILE_BODY(1, 0, tt + 1);
  }
#undef TILE_BODY
#undef MFMA_HALF
#undef READ_TILE

  // ---- fused QKV epilogue: row = bm + wr*64 + mf*16 + lhi*4 + i;
  //      col = bn + wc*16 + (nfi&1)*64 + (nfi>>1)*128 + l15
  u16* qp = (u16*)outp;
  u16* kp = qp + 16777216;  // 2*32*2048*128
  u16* vp = kp + 4194304;   // 2*8*2048*128
  if (bn < 5120) {
    const bool isQ = bn < 4096;
    u16* O = isQ ? qp : kp;
    const int hb = isQ ? (bn >> 7) : ((bn - 4096) >> 7);
    const int Hh = isQ ? NH_Q : NKV_H;
    const int j = wc * 16 + l15;  // 0..63
#pragma unroll
    for (int mf = 0; mf < 4; ++mf) {
      int rb = bm + wr * 64 + mf * 16 + lhi * 4;
#pragma unroll
      for (int p = 0; p < 2; ++p) {
        int head = hb + p;
#pragma unroll
        for (int i = 0; i < 4; ++i) {
          int m = rb + i;
          int b = m >> 11, srw = m & 2047;
          float c = cos_t[srw * 64 + j];
          float s = sin_t[srw * 64 + j];
          float x0 = acc[mf][2 * p][i];
          float x1 = acc[mf][2 * p + 1][i];
          size_t base = ((size_t)(b * Hh + head) * S_LEN + srw) * DHEAD;
          O[base + j] = f2bf(x0 * c - x1 * s);
          O[base + j + 64] = f2bf(x0 * s + x1 * c);
        }
      }
    }
  } else {  // V transposed [b][h][d][s]
#pragma unroll
    for (int mf = 0; mf < 4; ++mf) {
      int rb = bm + wr * 64 + mf * 16 + lhi * 4;
#pragma unroll
      for (int nfi = 0; nfi < 4; ++nfi) {
        int colrel = bn - 5120 + wc * 16 + (nfi & 1) * 64 + (nfi >> 1) * 128 + l15;
        int head = colrel >> 7, d = colrel & 127;
#pragma unroll
        for (int i = 0; i < 4; ++i) {
          int m = rb + i;
          int b = m >> 11, srw = m & 2047;
          vp[((size_t)(b * NKV_H + head) * DHEAD + d) * S_LEN + srw] = f2bf(acc[mf][nfi][i]);
        }
      }
    }
  }
}

// ---------------- pipelined 256x256 GEMM (out-proj): C = A*B^T, f32 out ----
// BK=32, 8 waves (4M x 2N, wave tile 64x128), 96KB triple-buffered LDS,
// 1 block/CU, grid 256 = 1 exact round. Same read-ahead TILE_BODY schedule:
// stage A(t+2) top / B(t+2) mid, counted vmcnt(4), 1 barrier/tile, double
// register sets, 12 ds_read_b128 + 32 MFMA per wave per tile.
__global__ __launch_bounds__(512, 1) void gemmo_kernel(
    const u16* __restrict__ A, const u16* __restrict__ B,
    float* __restrict__ C, int M, int N, int K) {
  __shared__ u16 LDS[49152];  // A 3 x 8192 elems at 0; B 3 x 8192 at 24576
  const int t = threadIdx.x;
  const int wave = t >> 6, lane = t & 63;
  const int l15 = lane & 15, lhi = lane >> 4;
  const int wr = wave >> 1, wc = wave & 1;
  const int gx = gridDim.x;
  const int nwg = gx * gridDim.y;
  const int id = blockIdx.y * gx + blockIdx.x;
  const int swz = (id & 7) * (nwg >> 3) + (id >> 3);
  const int bm = (swz / gx) * 256, bn = (swz % gx) * 256;

  // read offsets: elem = row*32 + ((lhi ^ sw) << 3), sw = (l15>>1)&3
  const int sw = (l15 >> 1) & 3;
  int aoff[4], boff[8];
#pragma unroll
  for (int mf = 0; mf < 4; ++mf)
    aoff[mf] = (wr * 64 + mf * 16 + l15) * 32 + ((lhi ^ sw) << 3);
#pragma unroll
  for (int nf = 0; nf < 8; ++nf)
    boff[nf] = (wc * 128 + nf * 16 + l15) * 32 + ((lhi ^ sw) << 3);

  // staging: 512 thr x 2 passes cover 256x32; row = t>>2 (+128 on pass 1)
  const int r0 = t >> 2;
  const int cs = (((t & 3) ^ ((t >> 3) & 3)) << 3);  // inverse swizzle

  const f32x4 fz = {0.f, 0.f, 0.f, 0.f};
  f32x4 acc[4][8];
#pragma unroll
  for (int mf = 0; mf < 4; ++mf)
#pragma unroll
    for (int nf = 0; nf < 8; ++nf) acc[mf][nf] = fz;

  auto stageA = [&](int tile, int buf) {  // 2 gloads (256 x 32)
    const size_t kb = (size_t)tile * 32;
    const u16* s0 = A + (size_t)(bm + r0) * K + kb + cs;
    u16* d = &LDS[buf * 8192 + (wave << 9)];
    gload16(s0, d);
    gload16(s0 + (size_t)128 * K, d + 4096);
  };
  auto stageB = [&](int tile, int buf) {  // 2 gloads (256 x 32)
    const size_t kb = (size_t)tile * 32;
    const u16* s0 = B + (size_t)(bn + r0) * K + kb + cs;
    u16* d = &LDS[24576 + buf * 8192 + (wave << 9)];
    gload16(s0, d);
    gload16(s0 + (size_t)128 * K, d + 4096);
  };

  s16x8 afr0[4], afr1[4], bfr0[8], bfr1[8];

#define READ_TILE(SET, BUF)                                                \
  do {                                                                     \
    const int _ab = (BUF) * 8192;                                          \
    const int _bb = 24576 + (BUF) * 8192;                                  \
    _Pragma("unroll") for (int mf = 0; mf < 4; ++mf)                       \
      afr##SET[mf] = *(const s16x8*)&LDS[_ab + aoff[mf]];                  \
    _Pragma("unroll") for (int nf = 0; nf < 8; ++nf)                       \
      bfr##SET[nf] = *(const s16x8*)&LDS[_bb + boff[nf]];                  \
  } while (0)

#define MFMA_HALF(SET, H)                                                  \
  do {                                                                     \
    __builtin_amdgcn_s_setprio(1);                                         \
    _Pragma("unroll") for (int mf = 0; mf < 4; ++mf)                       \
      _Pragma("unroll") for (int nf = 0; nf < 4; ++nf)                     \
        acc[mf][(H)*4 + nf] = __builtin_amdgcn_mfma_f32_16x16x32_bf16(     \
            afr##SET[mf], bfr##SET[(H)*4 + nf], acc[mf][(H)*4 + nf],       \
            0, 0, 0);                                                      \
    __builtin_amdgcn_s_setprio(0);                                         \
  } while (0)

#define TILE_BODY(SET, OSET, TT)                                           \
  do {                                                                     \
    const int _tt = (TT);                                                  \
    const bool _s2 = _tt + 2 < nt;                                         \
    if (_s2) stageA(_tt + 2, nx2);                                         \
    asm volatile("s_waitcnt lgkmcnt(0)" ::: "memory");                     \
    __builtin_amdgcn_sched_barrier(0);                                     \
    MFMA_HALF(SET, 0);                                                     \
    if (_s2) stageB(_tt + 2, nx2);                                         \
    if (_tt + 1 < nt) {                                                    \
      if (_s2) { asm volatile("s_waitcnt vmcnt(4)" ::: "memory"); }        \
      else     { asm volatile("s_waitcnt vmcnt(0)" ::: "memory"); }        \
      __builtin_amdgcn_sched_barrier(0);                                   \
      __builtin_amdgcn_s_barrier();                                        \
      __builtin_amdgcn_sched_barrier(0);                                   \
      READ_TILE(OSET, nxt1);                                               \
    }                                                                      \
    MFMA_HALF(SET, 1);                                                     \
    nxt1 = nx2;                                                            \
    nx2 = (nx2 == 2) ? 0 : nx2 + 1;                                        \
  } while (0)

  const int nt = K >> 5;
  stageA(0, 0); stageB(0, 0);
  stageA(1, 1); stageB(1, 1);
  asm volatile("s_waitcnt vmcnt(4)" ::: "memory");
  __builtin_amdgcn_sched_barrier(0);
  __builtin_amdgcn_s_barrier();
  __builtin_amdgcn_sched_barrier(0);
  READ_TILE(0, 0);

  int nxt1 = 1, nx2 = 2;
  for (int tt = 0; tt < nt; tt += 2) {
    TILE_BODY(0, 1, tt);
    TILE_BODY(1, 0, tt + 1);
  }
#undef TILE_BODY
#undef MFMA_HALF
#undef READ_TILE

  // epilogue: row = bm + wr*64 + mf*16 + lhi*4 + i; col = bn + wc*128 + nf*16 + l15
#pragma unroll
  for (int mf = 0; mf < 4; ++mf) {
    int rb = bm + wr * 64 + mf * 16 + lhi * 4;
#pragma unroll
    for (int nf = 0; nf < 8; ++nf) {
      int col = bn + wc * 128 + nf * 16 + l15;
#pragma unroll
      for (int i = 0; i < 4; ++i) C[(size_t)(rb + i) * N + col] = acc[mf][nf][i];
    }
  }
}

// ---------------- reg-staged GEMM (fallback path only) ----------------
template<int EPI, bool ABF16, bool BBF16>
__global__ __launch_bounds__(256) void gemm_kernel(
    const void* __restrict__ Aptr, const void* __restrict__ Bptr,
    void* __restrict__ outp, void* __restrict__ outp2, int M, int N, int K,
    const float* __restrict__ cos_t, const float* __restrict__ sin_t, int Hh) {
  __shared__ u16 As[128][72];
  __shared__ u16 Bs[128][72];
  const int t = threadIdx.x;
  const int wave = t >> 6, lane = t & 63;
  const int l15 = lane & 15, lhi = lane >> 4;
  const int gx = gridDim.x;
  const int nwg = gx * gridDim.y;
  const int id = blockIdx.y * gx + blockIdx.x;
  const int swz = (id & 7) * (nwg >> 3) + (id >> 3);
  const int bm = (swz / gx) * 128, bn = (swz % gx) * 128;

  const f32x4 fz = {0.f, 0.f, 0.f, 0.f};
  f32x4 acc[2][8];
#pragma unroll
  for (int a0 = 0; a0 < 2; ++a0)
#pragma unroll
    for (int b0 = 0; b0 < 8; ++b0) acc[a0][b0] = fz;

  for (int kt = 0; kt < K; kt += 64) {
    __syncthreads();
    if (ABF16) {
      const u16* A = (const u16*)Aptr;
#pragma unroll
      for (int p = 0; p < 4; ++p) {
        int row = p * 32 + (t >> 3), kc = (t & 7) * 8;
        *(s16x8*)&As[row][kc] = *(const s16x8*)(A + (size_t)(bm + row) * K + kt + kc);
      }
    } else {
      const float* A = (const float*)Aptr;
#pragma unroll
      for (int p = 0; p < 8; ++p) {
        int row = p * 16 + (t >> 4), kc = (t & 15) * 4;
        float4 f = *(const float4*)(A + (size_t)(bm + row) * K + kt + kc);
        unsigned* dst = (unsigned*)&As[row][kc];
        dst[0] = (unsigned)f2bf(f.x) | ((unsigned)f2bf(f.y) << 16);
        dst[1] = (unsigned)f2bf(f.z) | ((unsigned)f2bf(f.w) << 16);
      }
    }
    if (BBF16) {
      const u16* Bw = (const u16*)Bptr;
#pragma unroll
      for (int p = 0; p < 4; ++p) {
        int row = p * 32 + (t >> 3), kc = (t & 7) * 8;
        *(s16x8*)&Bs[row][kc] = *(const s16x8*)(Bw + (size_t)(bn + row) * K + kt + kc);
      }
    } else {
      const float* Bw = (const float*)Bptr;
#pragma unroll
      for (int p = 0; p < 8; ++p) {
        int row = p * 16 + (t >> 4), kc = (t & 15) * 4;
        float4 f = *(const float4*)(Bw + (size_t)(bn + row) * K + kt + kc);
        unsigned* dst = (unsigned*)&Bs[row][kc];
        dst[0] = (unsigned)f2bf(f.x) | ((unsigned)f2bf(f.y) << 16);
        dst[1] = (unsigned)f2bf(f.z) | ((unsigned)f2bf(f.w) << 16);
      }
    }
    __syncthreads();
#pragma unroll
    for (int ks = 0; ks < 2; ++ks) {
      s16x8 bfr[8];
#pragma unroll
      for (int nf = 0; nf < 8; ++nf)
        bfr[nf] = *(const s16x8*)&Bs[nf * 16 + l15][ks * 32 + lhi * 8];
#pragma unroll
      for (int mf = 0; mf < 2; ++mf) {
        s16x8 a = *(const s16x8*)&As[wave * 32 + mf * 16 + l15][ks * 32 + lhi * 8];
#pragma unroll
        for (int nf = 0; nf < 8; ++nf)
          acc[mf][nf] = __builtin_amdgcn_mfma_f32_16x16x32_bf16(a, bfr[nf], acc[mf][nf], 0, 0, 0);
      }
    }
  }

  if (EPI == 0) {
    float* C = (float*)outp;
#pragma unroll
    for (int mf = 0; mf < 2; ++mf)
#pragma unroll
      for (int nf = 0; nf < 8; ++nf) {
        int col = bn + nf * 16 + l15;
        int rb = bm + wave * 32 + mf * 16 + lhi * 4;
#pragma unroll
        for (int i = 0; i < 4; ++i) C[(size_t)(rb + i) * N + col] = acc[mf][nf][i];
      }
  } else if (EPI == 2) {
    u16* O = (u16*)outp;
    int h = bn >> 7;
#pragma unroll
    for (int mf = 0; mf < 2; ++mf)
#pragma unroll
      for (int nf = 0; nf < 4; ++nf) {
        int j = nf * 16 + l15;
        int rb = bm + wave * 32 + mf * 16 + lhi * 4;
#pragma unroll
        for (int i = 0; i < 4; ++i) {
          int m = rb + i;
          int b = m >> 11, srow = m & 2047;
          float c = cos_t[srow * 64 + j];
          float s = sin_t[srow * 64 + j];
          float x0 = acc[mf][nf][i];
          float x1 = acc[mf][nf + 4][i];
          size_t base = ((size_t)(b * Hh + h) * S_LEN + srow) * DHEAD;
          O[base + j] = f2bf(x0 * c - x1 * s);
          O[base + j + 64] = f2bf(x0 * s + x1 * c);
        }
      }
  } else {  // EPI == 4: bf16 transposed [b][h][d][s]
    u16* O = (u16*)outp;
#pragma unroll
    for (int mf = 0; mf < 2; ++mf)
#pragma unroll
      for (int nf = 0; nf < 8; ++nf) {
        int col = bn + nf * 16 + l15;
        int h = col >> 7, d = col & 127;
        int rb = bm + wave * 32 + mf * 16 + lhi * 4;
#pragma unroll
        for (int i = 0; i < 4; ++i) {
          int m = rb + i;
          int b = m >> 11, srow = m & 2047;
          O[((size_t)(b * Hh + h) * DHEAD + d) * S_LEN + srow] = f2bf(acc[mf][nf][i]);
        }
      }
  }
}

// ---------------- Flash attention (causal, GQA) ----------------
#define KIDX(r, c) (((r) * 128 + (c)) ^ (((r) & 7) << 3))
#define VIDX(d, kv) (((d) * 64 + (kv)) ^ (((d) & 7) << 3))
__global__ __launch_bounds__(512) void attn_kernel(
    const u16* __restrict__ q, const u16* __restrict__ k, const u16* __restrict__ vt,
    u16* __restrict__ ctx) {
  __shared__ u16 Ks[64 * 128];
  __shared__ u16 Vts[128 * 64];

  const int t = threadIdx.x;
  const int wave = t >> 6, lane = t & 63;
  const int l15 = lane & 15, lhi = lane >> 4;
  const int pi = blockIdx.x, h = blockIdx.y, b = blockIdx.z;
  const int kvh = h >> 2;
  const int qsub[2] = {pi, 15 - pi};
  const int ntiles = 32 - 2 * pi;

  const u16* qb = q + ((size_t)(b * NH_Q + h)) * S_LEN * DHEAD;
  const u16* kb = k + ((size_t)(b * NKV_H + kvh)) * S_LEN * DHEAD;
  const u16* vtb = vt + ((size_t)(b * NKV_H + kvh)) * DHEAD * S_LEN;

  s16x8 qf[2][4];
#pragma unroll
  for (int s = 0; s < 2; ++s)
#pragma unroll
    for (int ks = 0; ks < 4; ++ks)
      qf[s][ks] = *(const s16x8*)(qb + (size_t)(qsub[s] * 128 + wave * 16 + l15) * DHEAD +
                                  ks * 32 + lhi * 8);

  const f32x4 fz = {0.f, 0.f, 0.f, 0.f};
  f32x4 acc[2][8];
#pragma unroll
  for (int s = 0; s < 2; ++s)
#pragma unroll
    for (int i = 0; i < 8; ++i) acc[s][i] = fz;
  float mrow[2] = {-INFINITY, -INFINITY};
  float lsum[2] = {0.f, 0.f};

  const float scale = 0.08838834764831845f;

  const int sl0 = l15 | (((2 * lhi) & 3) << 4);
  const int sl1 = sl0 | 16;
  const bool hisel = (lhi & 2) != 0;

  const int krow = t >> 3, kd0 = (t & 7) * 16;
  const int vrow = t >> 2, vk0 = (t & 3) * 16;
  s16x8 kr0, kr1, vr0, vr1;
  {
    const u16* p = kb + (size_t)krow * DHEAD + kd0;
    kr0 = *(const s16x8*)p;
    kr1 = *(const s16x8*)(p + 8);
    const u16* pv = vtb + (size_t)vrow * S_LEN + vk0;
    vr0 = *(const s16x8*)pv;
    vr1 = *(const s16x8*)(pv + 8);
  }

  for (int tt = 0; tt < ntiles; ++tt) {
    __syncthreads();
    *(s16x8*)&Ks[KIDX(krow, kd0)] = kr0;
    *(s16x8*)&Ks[KIDX(krow, kd0 + 8)] = kr1;
    *(s16x8*)&Vts[VIDX(vrow, vk0)] = vr0;
    *(s16x8*)&Vts[VIDX(vrow, vk0 + 8)] = vr1;
    __syncthreads();
    if (tt + 1 < ntiles) {
      const u16* p = kb + (size_t)((tt + 1) * 64 + krow) * DHEAD + kd0;
      kr0 = *(const s16x8*)p;
      kr1 = *(const s16x8*)(p + 8);
      const u16* pv = vtb + (size_t)vrow * S_LEN + (tt + 1) * 64 + vk0;
      vr0 = *(const s16x8*)pv;
      vr1 = *(const s16x8*)(pv + 8);
    }

    const int kc_base = tt * 64;
#pragma unroll
    for (int s = 0; s < 2; ++s) {
      const int wmin = qsub[s] * 128 + wave * 16;
      if (kc_base > wmin + 15) continue;
      f32x4 sacc[4];
#pragma unroll
      for (int i = 0; i < 4; ++i) sacc[i] = fz;
      __builtin_amdgcn_s_setprio(1);
#pragma unroll
      for (int ks = 0; ks < 4; ++ks) {
#pragma unroll
        for (int nf = 0; nf < 4; ++nf) {
          s16x8 kf = *(const s16x8*)&Ks[KIDX(nf * 16 + l15, ks * 32 + lhi * 8)];
          sacc[nf] = __builtin_amdgcn_mfma_f32_16x16x32_bf16(kf, qf[s][ks], sacc[nf], 0, 0, 0);
        }
      }
      __builtin_amdgcn_s_setprio(0);

      const int qg = wmin + l15;
      float pmax = -INFINITY;
      if (kc_base + 63 > wmin) {
#pragma unroll
        for (int nf = 0; nf < 4; ++nf)
#pragma unroll
          for (int i = 0; i < 4; ++i) {
            int kv = kc_base + nf * 16 + lhi * 4 + i;
            float sv = sacc[nf][i] * scale;
            sv = (kv <= qg) ? sv : -INFINITY;
            sacc[nf][i] = sv;
            pmax = fmaxf(pmax, sv);
          }
      } else {
#pragma unroll
        for (int nf = 0; nf < 4; ++nf)
#pragma unroll
          for (int i = 0; i < 4; ++i) {
            float sv = sacc[nf][i] * scale;
            sacc[nf][i] = sv;
            pmax = fmaxf(pmax, sv);
          }
      }
      pmax = fmaxf(pmax, __shfl_xor(pmax, 16, 64));
      pmax = fmaxf(pmax, __shfl_xor(pmax, 32, 64));

      if (!__all(pmax <= mrow[s] + 8.0f)) {
        float mnew = fmaxf(mrow[s], pmax);
        float alpha = __expf(mrow[s] - mnew);
        mrow[s] = mnew;
        lsum[s] *= alpha;
#pragma unroll
        for (int i = 0; i < 4; ++i) {
          float al = __shfl(alpha, (lane & 48) | (lhi * 4 + i), 64);
#pragma unroll
          for (int df = 0; df < 8; ++df) acc[s][df][i] *= al;
        }
      }

      float rsum = 0.f;
      unsigned pk[4][2];
#pragma unroll
      for (int nf = 0; nf < 4; ++nf) {
        float p0 = __expf(sacc[nf][0] - mrow[s]);
        float p1 = __expf(sacc[nf][1] - mrow[s]);
        float p2 = __expf(sacc[nf][2] - mrow[s]);
        float p3 = __expf(sacc[nf][3] - mrow[s]);
        rsum += (p0 + p1) + (p2 + p3);
        pk[nf][0] = (unsigned)f2bf(p0) | ((unsigned)f2bf(p1) << 16);
        pk[nf][1] = (unsigned)f2bf(p2) | ((unsigned)f2bf(p3) << 16);
      }
      rsum += __shfl_xor(rsum, 16, 64);
      rsum += __shfl_xor(rsum, 32, 64);
      lsum[s] += rsum;

      s16x8 pa[2];
#pragma unroll
      for (int ph = 0; ph < 2; ++ph) {
        unsigned lo0 = __shfl((int)pk[2 * ph][0], sl0, 64);
        unsigned hi0 = __shfl((int)pk[2 * ph + 1][0], sl0, 64);
        unsigned lo1 = __shfl((int)pk[2 * ph][1], sl0, 64);
        unsigned hi1 = __shfl((int)pk[2 * ph + 1][1], sl0, 64);
        unsigned lo2 = __shfl((int)pk[2 * ph][0], sl1, 64);
        unsigned hi2 = __shfl((int)pk[2 * ph + 1][0], sl1, 64);
        unsigned lo3 = __shfl((int)pk[2 * ph][1], sl1, 64);
        unsigned hi3 = __shfl((int)pk[2 * ph + 1][1], sl1, 64);
        u32x4 w;
        w[0] = hisel ? hi0 : lo0;
        w[1] = hisel ? hi1 : lo1;
        w[2] = hisel ? hi2 : lo2;
        w[3] = hisel ? hi3 : lo3;
        pa[ph] = __builtin_bit_cast(s16x8, w);
      }

      __builtin_amdgcn_s_setprio(1);
#pragma unroll
      for (int ph = 0; ph < 2; ++ph) {
#pragma unroll
        for (int df = 0; df < 8; ++df) {
          s16x8 bb = *(const s16x8*)&Vts[VIDX(df * 16 + l15, ph * 32 + lhi * 8)];
          acc[s][df] = __builtin_amdgcn_mfma_f32_16x16x32_bf16(pa[ph], bb, acc[s][df], 0, 0, 0);
        }
      }
      __builtin_amdgcn_s_setprio(0);
    }
  }

#pragma unroll
  for (int s = 0; s < 2; ++s) {
    float rl = 1.0f / lsum[s];
#pragma unroll
    for (int i = 0; i < 4; ++i) {
      float rli = __shfl(rl, (lane & 48) | (lhi * 4 + i), 64);
      int m = b * S_LEN + qsub[s] * 128 + wave * 16 + lhi * 4 + i;
#pragma unroll
      for (int df = 0; df < 8; ++df) {
        int col = h * DHEAD + df * 16 + l15;
        ctx[(size_t)m * (NH_Q * DHEAD) + col] = f2bf(acc[s][df][i] * rli);
      }
    }
  }
}

extern "C" void kernel_launch(void* const* d_in, const int* in_sizes, int n_in,
                              void* d_out, int out_size, void* d_ws, size_t ws_size,
                              hipStream_t stream) {
  const float* x = (const float*)d_in[0];
  const int* positions = (const int*)d_in[1];
  const float* wq = (const float*)d_in[2];
  const float* wk = (const float*)d_in[3];
  const float* wv = (const float*)d_in[4];
  const float* wo = (const float*)d_in[5];
  float* out = (float*)d_out;

  char* ws = (char*)d_ws;
  const size_t MB1 = 1048576;
  const size_t SZ_X = 33554432;     // 2*2048*4096 bf16
  const size_t SZ_WQKV = 50331648;  // 6144*4096 bf16
  const size_t SZ_WO = 33554432;    // 4096*4096 bf16
  const size_t SZ_Q = 33554432;     // q bf16
  const size_t SZ_WK = 8388608;     // k or v bf16
  const size_t NEED_FULL = MB1 + SZ_X + SZ_WQKV + SZ_Q + 2 * SZ_WK;  // 129 MB
  const size_t NEED_WO = NEED_FULL + SZ_WO;                          // 161 MB

  float* cos_t = (float*)ws;
  float* sin_t = (float*)(ws + MB1 / 2);

  if (ws_size >= NEED_WO) {
    char* p = ws + MB1;
    u16* x_bf = (u16*)p;    p += SZ_X;     // later reused as ctx
    u16* wqkv_bf = (u16*)p; p += SZ_WQKV;  // wq|wk|wv stacked
    u16* wo_bf = (u16*)p;   p += SZ_WO;
    u16* q_ws = (u16*)p;    p += SZ_Q;     // q | k | v contiguous
    u16* k_ws = (u16*)p;    p += SZ_WK;
    u16* v_ws = (u16*)p;    p += SZ_WK;
    u16* ctx_ws = x_bf;

    cvt_all_kernel<<<2048, 256, 0, stream>>>(x, wq, wk, wv, wo, x_bf, wqkv_bf, wo_bf,
                                             positions, cos_t, sin_t, 1);
    // fused QKV: 128x256 tiles (R12 engine), grid (24,32) = 768 = 3 exact rounds
    gemmp_kernel<5><<<dim3(24, 32), 512, 0, stream>>>(
        x_bf, wqkv_bf, q_ws, 4096, 6144, 4096, cos_t, sin_t);
    attn_kernel<<<dim3(8, 32, 2), 512, 0, stream>>>(q_ws, k_ws, v_ws, ctx_ws);
    // out-proj: 256x256 tiles, grid (16,16) = 256 = 1 exact round
    gemmo_kernel<<<dim3(16, 16), 512, 0, stream>>>(
        ctx_ws, wo_bf, out, 4096, 4096, 4096);
  } else if (ws_size >= NEED_FULL) {
    char* p = ws + MB1;
    u16* x_bf = (u16*)p;    p += SZ_X;
    u16* wqkv_bf = (u16*)p; p += SZ_WQKV;
    u16* q_ws = (u16*)p;    p += SZ_Q;
    u16* k_ws = (u16*)p;    p += SZ_WK;
    u16* v_ws = (u16*)p;    p += SZ_WK;
    u16* ctx_ws = x_bf;

    cvt_all_kernel<<<2048, 256, 0, stream>>>(x, wq, wk, wv, nullptr, x_bf, wqkv_bf, nullptr,
                                             positions, cos_t, sin_t, 0);
    gemmp_kernel<5><<<dim3(24, 32), 512, 0, stream>>>(
        x_bf, wqkv_bf, q_ws, 4096, 6144, 4096, cos_t, sin_t);
    cvt_kernel<<<2048, 256, 0, stream>>>(wo, wqkv_bf, 4194304);  // wqkv_bf now = wo_bf
    attn_kernel<<<dim3(8, 32, 2), 512, 0, stream>>>(q_ws, k_ws, v_ws, ctx_ws);
    gemmo_kernel<<<dim3(16, 16), 512, 0, stream>>>(
        ctx_ws, wqkv_bf, out, 4096, 4096, 4096);
  } else {
    u16* q_ws = (u16*)(ws + MB1);
    u16* k_ws = (u16*)(ws + MB1 + SZ_Q);
    u16* v_ws = (u16*)(ws + MB1 + SZ_Q + SZ_WK);
    u16* ctx_ws = (u16*)(ws + MB1 + SZ_Q + 2 * SZ_WK);

    rope_table_kernel<<<512, 256, 0, stream>>>(positions, cos_t, sin_t);
    gemm_kernel<2, false, false><<<dim3(32, 32), 256, 0, stream>>>(
        x, wq, q_ws, nullptr, 4096, 4096, 4096, cos_t, sin_t, NH_Q);
    gemm_kernel<2, false, false><<<dim3(8, 32), 256, 0, stream>>>(
        x, wk, k_ws, nullptr, 4096, 1024, 4096, cos_t, sin_t, NKV_H);
    gemm_kernel<4, false, false><<<dim3(8, 32), 256, 0, stream>>>(
        x, wv, v_ws, nullptr, 4096, 1024, 4096, nullptr, nullptr, NKV_H);
    attn_kernel<<<dim3(8, 32, 2), 512, 0, stream>>>(q_ws, k_ws, v_ws, ctx_ws);
    gemm_kernel<0, true, false><<<dim3(32, 32), 256, 0, stream>>>(
        ctx_ws, wo, out, nullptr, 4096, 4096, 4096, nullptr, nullptr, 0);
  }
}

// Round 15
// 518.265 us; speedup vs baseline: 1.0957x; 1.0081x over previous
//
#include <hip/hip_runtime.h>
#include <math.h>

typedef short s16x8 __attribute__((ext_vector_type(8)));
typedef float f32x4 __attribute__((ext_vector_type(4)));
typedef unsigned u32x4 __attribute__((ext_vector_type(4)));
typedef unsigned short u16;

#define S_LEN 2048
#define HID_DIM 4096
#define NH_Q 32
#define NKV_H 8
#define DHEAD 128

__device__ __forceinline__ u16 f2bf(float f) {
  unsigned u = __builtin_bit_cast(unsigned, f);
  u += 0x7fffu + ((u >> 16) & 1u);
  return (u16)(u >> 16);
}

// async global -> LDS, 16B per lane; lds base wave-uniform, lane*16 auto-offset
__device__ __forceinline__ void gload16(const u16* g, u16* l) {
  __builtin_amdgcn_global_load_lds(
      (const __attribute__((address_space(1))) void*)g,
      (__attribute__((address_space(3))) void*)l, 16, 0, 0);
}

// ---------------- f32 -> bf16 bulk convert (single region) ----------------
__global__ void cvt_kernel(const float* __restrict__ in, u16* __restrict__ out, int n4) {
  int stride = gridDim.x * blockDim.x;
  for (int i = blockIdx.x * blockDim.x + threadIdx.x; i < n4; i += stride) {
    float4 f = ((const float4*)in)[i];
    uint2 o;
    o.x = (unsigned)f2bf(f.x) | ((unsigned)f2bf(f.y) << 16);
    o.y = (unsigned)f2bf(f.z) | ((unsigned)f2bf(f.w) << 16);
    ((uint2*)out)[i] = o;
  }
}

// ---- fused: x|wq|wk|wv[|wo] f32->bf16 + RoPE tables, one launch ----
__global__ void cvt_all_kernel(const float* __restrict__ x, const float* __restrict__ wq,
                               const float* __restrict__ wk, const float* __restrict__ wv,
                               const float* __restrict__ wo, u16* __restrict__ x_bf,
                               u16* __restrict__ wqkv_bf, u16* __restrict__ wo_bf,
                               const int* __restrict__ positions, float* __restrict__ cos_t,
                               float* __restrict__ sin_t, int with_wo) {
  const int R0 = 4194304, R1 = 8388608, R2 = 9437184, R3 = 10485760, R4 = 14680064;
  const int cvt_end = with_wo ? R4 : R3;
  const int rope_units = 32768;  // 2048*64 / 4
  const int total = cvt_end + rope_units;
  const int stride = gridDim.x * blockDim.x;
  for (int i = blockIdx.x * blockDim.x + threadIdx.x; i < total; i += stride) {
    if (i < cvt_end) {
      const float* src;
      u16* dst;
      int off;
      if (i < R0)      { src = x;  dst = x_bf;               off = i; }
      else if (i < R1) { src = wq; dst = wqkv_bf;            off = i - R0; }
      else if (i < R2) { src = wk; dst = wqkv_bf + 16777216; off = i - R1; }
      else if (i < R3) { src = wv; dst = wqkv_bf + 20971520; off = i - R2; }
      else             { src = wo; dst = wo_bf;              off = i - R3; }
      float4 f = ((const float4*)src)[off];
      uint2 o;
      o.x = (unsigned)f2bf(f.x) | ((unsigned)f2bf(f.y) << 16);
      o.y = (unsigned)f2bf(f.z) | ((unsigned)f2bf(f.w) << 16);
      ((uint2*)dst)[off] = o;
    } else {
      int base = (i - cvt_end) * 4;
#pragma unroll
      for (int e = 0; e < 4; ++e) {
        int idx = base + e;
        int s = idx >> 6, j = idx & 63;
        float pos = (float)positions[s];
        float inv = expf(-(float)j * (9.210340371976184f / 64.0f));
        float sv, cv;
        sincosf(pos * inv, &sv, &cv);
        cos_t[idx] = cv;
        sin_t[idx] = sv;
      }
    }
  }
}

// ---------------- RoPE tables (fallback path) ----------------
__global__ void rope_table_kernel(const int* __restrict__ positions,
                                  float* __restrict__ cos_t, float* __restrict__ sin_t) {
  int idx = blockIdx.x * 256 + threadIdx.x;
  if (idx >= S_LEN * 64) return;
  int s = idx >> 6, j = idx & 63;
  float pos = (float)positions[s];
  float inv = expf(-(float)j * (9.210340371976184f / 64.0f));
  float sv, cv;
  sincosf(pos * inv, &sv, &cv);
  cos_t[idx] = cv;
  sin_t[idx] = sv;
}

// ---------------- pipelined 128x256 GEMM (R12 engine): C = A[M][K]*B[N][K]^T ----
// BK=64, 8 waves (2M x 4N), 144KB triple-buffered LDS, 1 block/CU.
// READ-AHEAD pipeline + counted vmcnt(6). Per-XCD COLUMN-SLAB block mapping:
// each XCD owns a contiguous bx-slab (gx/8 B-panels x all by); the 32
// concurrent blocks on an XCD share ONE 2MB B-panel (L2-resident), A streams.
// EPI: 5 = fused QKV (outp = q; k = q+16777216, v = k+4194304;
//      Q/K RoPE'd [b][h][s][d], V^T [b][h][d][s])
template<int EPI>
__global__ __launch_bounds__(512, 2) void gemmp_kernel(
    const u16* __restrict__ A, const u16* __restrict__ B,
    void* __restrict__ outp, int M, int N, int K,
    const float* __restrict__ cos_t, const float* __restrict__ sin_t) {
  __shared__ u16 LDS[73728];  // A 3 x 8192 elems at 0; B 3 x 16384 at 24576
  const int t = threadIdx.x;
  const int wave = t >> 6, lane = t & 63;
  const int l15 = lane & 15, lhi = lane >> 4;
  const int wr = wave >> 2, wc = wave & 3;
  const int gx = gridDim.x;
  const int nwg = gx * gridDim.y;
  const int id = blockIdx.y * gx + blockIdx.x;
  // per-XCD column-slab mapping (bijective; gx % 8 == 0 or nwg/gx slabs even)
  const int xcd = id & 7, cid = id >> 3;
  const int npx = gx >> 3;          // bx-panels per XCD slab
  const int gy = nwg / gx;          // M-blocks
  const int bxi = xcd * npx + cid / gy;
  const int byi = cid % gy;
  const int bm = byi * 128, bn = bxi * 256;

  const int sw = l15 & 7;
  int aoff[4][2], boff[2][2];
#pragma unroll
  for (int q = 0; q < 4; ++q)
#pragma unroll
    for (int ks = 0; ks < 2; ++ks)
      aoff[q][ks] = wr * 4096 + (q * 16 + l15) * 64 + (((ks << 2) + lhi) ^ sw) * 8;
#pragma unroll
  for (int f = 0; f < 2; ++f)
#pragma unroll
    for (int ks = 0; ks < 2; ++ks)
      boff[f][ks] = (f * 64 + wc * 16 + l15) * 64 + (((ks << 2) + lhi) ^ sw) * 8;

  const int lr1 = t >> 3;                     // 0..63
  const int cs1 = ((t & 7) ^ (lr1 & 7)) * 8;  // inverse swizzle
  const int ldsw = wave * 512;

  const f32x4 fz = {0.f, 0.f, 0.f, 0.f};
  f32x4 acc[4][4];
#pragma unroll
  for (int mf = 0; mf < 4; ++mf)
#pragma unroll
    for (int nf = 0; nf < 4; ++nf) acc[mf][nf] = fz;

  auto stageA = [&](int tile, int buf) {
    const size_t kb = (size_t)tile * 64;
    gload16(A + (size_t)(bm + lr1) * K + kb + cs1, &LDS[buf * 8192 + ldsw]);
    gload16(A + (size_t)(bm + 64 + lr1) * K + kb + cs1, &LDS[buf * 8192 + 4096 + ldsw]);
  };
  auto stageB = [&](int tile, int h, int buf) {
    const size_t kb = (size_t)tile * 64;
    gload16(B + (size_t)(bn + h * 128 + lr1) * K + kb + cs1,
            &LDS[24576 + buf * 16384 + h * 8192 + ldsw]);
    gload16(B + (size_t)(bn + h * 128 + 64 + lr1) * K + kb + cs1,
            &LDS[24576 + buf * 16384 + h * 8192 + 4096 + ldsw]);
  };

  s16x8 afr0[4][2], afr1[4][2];
  s16x8 bfr00[2][2], bfr01[2][2];
  s16x8 bfr10[2][2], bfr11[2][2];

#define READ_TILE(SET, BUF)                                                \
  do {                                                                     \
    const int _b = (BUF);                                                  \
    const int _ba = _b * 8192;                                             \
    _Pragma("unroll") for (int q = 0; q < 4; ++q)                          \
      _Pragma("unroll") for (int ks = 0; ks < 2; ++ks)                     \
        afr##SET[q][ks] = *(const s16x8*)&LDS[_ba + aoff[q][ks]];          \
    const int _b0 = 24576 + _b * 16384;                                    \
    _Pragma("unroll") for (int f = 0; f < 2; ++f)                          \
      _Pragma("unroll") for (int ks = 0; ks < 2; ++ks)                     \
        bfr0##SET[f][ks] = *(const s16x8*)&LDS[_b0 + boff[f][ks]];         \
    const int _b1 = _b0 + 8192;                                            \
    _Pragma("unroll") for (int f = 0; f < 2; ++f)                          \
      _Pragma("unroll") for (int ks = 0; ks < 2; ++ks)                     \
        bfr1##SET[f][ks] = *(const s16x8*)&LDS[_b1 + boff[f][ks]];         \
  } while (0)

#define MFMA_HALF(SET, NFH, BH)                                            \
  do {                                                                     \
    __builtin_amdgcn_s_setprio(1);                                         \
    _Pragma("unroll") for (int q = 0; q < 4; ++q)                          \
      _Pragma("unroll") for (int f = 0; f < 2; ++f)                        \
        _Pragma("unroll") for (int ks = 0; ks < 2; ++ks)                   \
          acc[q][(NFH)*2 + f] = __builtin_amdgcn_mfma_f32_16x16x32_bf16(   \
              afr##SET[q][ks], bfr##BH##SET[f][ks], acc[q][(NFH)*2 + f],   \
              0, 0, 0);                                                    \
    __builtin_amdgcn_s_setprio(0);                                         \
  } while (0)

#define TILE_BODY(SET, OSET, TT)                                           \
  do {                                                                     \
    const int _tt = (TT);                                                  \
    const bool _s2 = _tt + 2 < nt;                                         \
    if (_s2) { stageA(_tt + 2, nx2); stageB(_tt + 2, 0, nx2); }            \
    asm volatile("s_waitcnt lgkmcnt(0)" ::: "memory");                     \
    __builtin_amdgcn_sched_barrier(0);                                     \
    MFMA_HALF(SET, 0, 0);                                                  \
    if (_s2) stageB(_tt + 2, 1, nx2);                                      \
    if (_tt + 1 < nt) {                                                    \
      if (_s2) { asm volatile("s_waitcnt vmcnt(6)" ::: "memory"); }        \
      else     { asm volatile("s_waitcnt vmcnt(0)" ::: "memory"); }        \
      __builtin_amdgcn_sched_barrier(0);                                   \
      __builtin_amdgcn_s_barrier();                                        \
      __builtin_amdgcn_sched_barrier(0);                                   \
      READ_TILE(OSET, nxt1);                                               \
    }                                                                      \
    MFMA_HALF(SET, 1, 1);                                                  \
    nxt1 = nx2;                                                            \
    nx2 = (nx2 == 2) ? 0 : nx2 + 1;                                        \
  } while (0)

  const int nt = K >> 6;
  stageA(0, 0); stageB(0, 0, 0); stageB(0, 1, 0);
  stageA(1, 1); stageB(1, 0, 1); stageB(1, 1, 1);
  asm volatile("s_waitcnt vmcnt(6)" ::: "memory");
  __builtin_amdgcn_sched_barrier(0);
  __builtin_amdgcn_s_barrier();
  __builtin_amdgcn_sched_barrier(0);
  READ_TILE(0, 0);

  int nxt1 = 1, nx2 = 2;
  for (int tt = 0; tt < nt; tt += 2) {
    TILE_BODY(0, 1, tt);
    TILE_BODY(1, 0, tt + 1);
  }
#undef TILE_BODY
#undef MFMA_HALF
#undef READ_TILE

  // ---- fused QKV epilogue: row = bm + wr*64 + mf*16 + lhi*4 + i;
  //      col = bn + wc*16 + (nfi&1)*64 + (nfi>>1)*128 + l15
  u16* qp = (u16*)outp;
  u16* kp = qp + 16777216;  // 2*32*2048*128
  u16* vp = kp + 4194304;   // 2*8*2048*128
  if (bn < 5120) {
    const bool isQ = bn < 4096;
    u16* O = isQ ? qp : kp;
    const int hb = isQ ? (bn >> 7) : ((bn - 4096) >> 7);
    const int Hh = isQ ? NH_Q : NKV_H;
    const int j = wc * 16 + l15;  // 0..63
#pragma unroll
    for (int mf = 0; mf < 4; ++mf) {
      int rb = bm + wr * 64 + mf * 16 + lhi * 4;
#pragma unroll
      for (int p = 0; p < 2; ++p) {
        int head = hb + p;
#pragma unroll
        for (int i = 0; i < 4; ++i) {
          int m = rb + i;
          int b = m >> 11, srw = m & 2047;
          float c = cos_t[srw * 64 + j];
          float s = sin_t[srw * 64 + j];
          float x0 = acc[mf][2 * p][i];
          float x1 = acc[mf][2 * p + 1][i];
          size_t base = ((size_t)(b * Hh + head) * S_LEN + srw) * DHEAD;
          O[base + j] = f2bf(x0 * c - x1 * s);
          O[base + j + 64] = f2bf(x0 * s + x1 * c);
        }
      }
    }
  } else {  // V transposed [b][h][d][s]
#pragma unroll
    for (int mf = 0; mf < 4; ++mf) {
      int rb = bm + wr * 64 + mf * 16 + lhi * 4;
#pragma unroll
      for (int nfi = 0; nfi < 4; ++nfi) {
        int colrel = bn - 5120 + wc * 16 + (nfi & 1) * 64 + (nfi >> 1) * 128 + l15;
        int head = colrel >> 7, d = colrel & 127;
#pragma unroll
        for (int i = 0; i < 4; ++i) {
          int m = rb + i;
          int b = m >> 11, srw = m & 2047;
          vp[((size_t)(b * NKV_H + head) * DHEAD + d) * S_LEN + srw] = f2bf(acc[mf][nfi][i]);
        }
      }
    }
  }
}

// ---------------- pipelined 256x256 GEMM (out-proj): C = A*B^T, f32 out ----
// BK=32, 8 waves (4M x 2N, wave tile 64x128), 48KB triple-buffered LDS,
// grid 256 = 1 exact round; per-XCD column-slab mapping (2 B-panels/XCD).
__global__ __launch_bounds__(512, 1) void gemmo_kernel(
    const u16* __restrict__ A, const u16* __restrict__ B,
    float* __restrict__ C, int M, int N, int K) {
  __shared__ u16 LDS[49152];  // A 3 x 8192 elems at 0; B 3 x 8192 at 24576
  const int t = threadIdx.x;
  const int wave = t >> 6, lane = t & 63;
  const int l15 = lane & 15, lhi = lane >> 4;
  const int wr = wave >> 1, wc = wave & 1;
  const int gx = gridDim.x;
  const int nwg = gx * gridDim.y;
  const int id = blockIdx.y * gx + blockIdx.x;
  // per-XCD column-slab mapping
  const int xcd = id & 7, cid = id >> 3;
  const int npx = gx >> 3;
  const int gy = nwg / gx;
  const int bxi = xcd * npx + cid / gy;
  const int byi = cid % gy;
  const int bm = byi * 256, bn = bxi * 256;

  // read offsets: elem = row*32 + ((lhi ^ sw) << 3), sw = (l15>>1)&3
  const int sw = (l15 >> 1) & 3;
  int aoff[4], boff[8];
#pragma unroll
  for (int mf = 0; mf < 4; ++mf)
    aoff[mf] = (wr * 64 + mf * 16 + l15) * 32 + ((lhi ^ sw) << 3);
#pragma unroll
  for (int nf = 0; nf < 8; ++nf)
    boff[nf] = (wc * 128 + nf * 16 + l15) * 32 + ((lhi ^ sw) << 3);

  const int r0 = t >> 2;
  const int cs = (((t & 3) ^ ((t >> 3) & 3)) << 3);  // inverse swizzle

  const f32x4 fz = {0.f, 0.f, 0.f, 0.f};
  f32x4 acc[4][8];
#pragma unroll
  for (int mf = 0; mf < 4; ++mf)
#pragma unroll
    for (int nf = 0; nf < 8; ++nf) acc[mf][nf] = fz;

  auto stageA = [&](int tile, int buf) {
    const size_t kb = (size_t)tile * 32;
    const u16* s0 = A + (size_t)(bm + r0) * K + kb + cs;
    u16* d = &LDS[buf * 8192 + (wave << 9)];
    gload16(s0, d);
    gload16(s0 + (size_t)128 * K, d + 4096);
  };
  auto stageB = [&](int tile, int buf) {
    const size_t kb = (size_t)tile * 32;
    const u16* s0 = B + (size_t)(bn + r0) * K + kb + cs;
    u16* d = &LDS[24576 + buf * 8192 + (wave << 9)];
    gload16(s0, d);
    gload16(s0 + (size_t)128 * K, d + 4096);
  };

  s16x8 afr0[4], afr1[4], bfr0[8], bfr1[8];

#define READ_TILE(SET, BUF)                                                \
  do {                                                                     \
    const int _ab = (BUF) * 8192;                                          \
    const int _bb = 24576 + (BUF) * 8192;                                  \
    _Pragma("unroll") for (int mf = 0; mf < 4; ++mf)                       \
      afr##SET[mf] = *(const s16x8*)&LDS[_ab + aoff[mf]];                  \
    _Pragma("unroll") for (int nf = 0; nf < 8; ++nf)                       \
      bfr##SET[nf] = *(const s16x8*)&LDS[_bb + boff[nf]];                  \
  } while (0)

#define MFMA_HALF(SET, H)                                                  \
  do {                                                                     \
    __builtin_amdgcn_s_setprio(1);                                         \
    _Pragma("unroll") for (int mf = 0; mf < 4; ++mf)                       \
      _Pragma("unroll") for (int nf = 0; nf < 4; ++nf)                     \
        acc[mf][(H)*4 + nf] = __builtin_amdgcn_mfma_f32_16x16x32_bf16(     \
            afr##SET[mf], bfr##SET[(H)*4 + nf], acc[mf][(H)*4 + nf],       \
            0, 0, 0);                                                      \
    __builtin_amdgcn_s_setprio(0);                                         \
  } while (0)

#define TILE_BODY(SET, OSET, TT)                                           \
  do {                                                                     \
    const int _tt = (TT);                                                  \
    const bool _s2 = _tt + 2 < nt;                                         \
    if (_s2) stageA(_tt + 2, nx2);                                         \
    asm volatile("s_waitcnt lgkmcnt(0)" ::: "memory");                     \
    __builtin_amdgcn_sched_barrier(0);                                     \
    MFMA_HALF(SET, 0);                                                     \
    if (_s2) stageB(_tt + 2, nx2);                                         \
    if (_tt + 1 < nt) {                                                    \
      if (_s2) { asm volatile("s_waitcnt vmcnt(4)" ::: "memory"); }        \
      else     { asm volatile("s_waitcnt vmcnt(0)" ::: "memory"); }        \
      __builtin_amdgcn_sched_barrier(0);                                   \
      __builtin_amdgcn_s_barrier();                                        \
      __builtin_amdgcn_sched_barrier(0);                                   \
      READ_TILE(OSET, nxt1);                                               \
    }                                                                      \
    MFMA_HALF(SET, 1);                                                     \
    nxt1 = nx2;                                                            \
    nx2 = (nx2 == 2) ? 0 : nx2 + 1;                                        \
  } while (0)

  const int nt = K >> 5;
  stageA(0, 0); stageB(0, 0);
  stageA(1, 1); stageB(1, 1);
  asm volatile("s_waitcnt vmcnt(4)" ::: "memory");
  __builtin_amdgcn_sched_barrier(0);
  __builtin_amdgcn_s_barrier();
  __builtin_amdgcn_sched_barrier(0);
  READ_TILE(0, 0);

  int nxt1 = 1, nx2 = 2;
  for (int tt = 0; tt < nt; tt += 2) {
    TILE_BODY(0, 1, tt);
    TILE_BODY(1, 0, tt + 1);
  }
#undef TILE_BODY
#undef MFMA_HALF
#undef READ_TILE

#pragma unroll
  for (int mf = 0; mf < 4; ++mf) {
    int rb = bm + wr * 64 + mf * 16 + lhi * 4;
#pragma unroll
    for (int nf = 0; nf < 8; ++nf) {
      int col = bn + wc * 128 + nf * 16 + l15;
#pragma unroll
      for (int i = 0; i < 4; ++i) C[(size_t)(rb + i) * N + col] = acc[mf][nf][i];
    }
  }
}

// ---------------- reg-staged GEMM (fallback path only) ----------------
template<int EPI, bool ABF16, bool BBF16>
__global__ __launch_bounds__(256) void gemm_kernel(
    const void* __restrict__ Aptr, const void* __restrict__ Bptr,
    void* __restrict__ outp, void* __restrict__ outp2, int M, int N, int K,
    const float* __restrict__ cos_t, const float* __restrict__ sin_t, int Hh) {
  __shared__ u16 As[128][72];
  __shared__ u16 Bs[128][72];
  const int t = threadIdx.x;
  const int wave = t >> 6, lane = t & 63;
  const int l15 = lane & 15, lhi = lane >> 4;
  const int gx = gridDim.x;
  const int nwg = gx * gridDim.y;
  const int id = blockIdx.y * gx + blockIdx.x;
  const int swz = (id & 7) * (nwg >> 3) + (id >> 3);
  const int bm = (swz / gx) * 128, bn = (swz % gx) * 128;

  const f32x4 fz = {0.f, 0.f, 0.f, 0.f};
  f32x4 acc[2][8];
#pragma unroll
  for (int a0 = 0; a0 < 2; ++a0)
#pragma unroll
    for (int b0 = 0; b0 < 8; ++b0) acc[a0][b0] = fz;

  for (int kt = 0; kt < K; kt += 64) {
    __syncthreads();
    if (ABF16) {
      const u16* A = (const u16*)Aptr;
#pragma unroll
      for (int p = 0; p < 4; ++p) {
        int row = p * 32 + (t >> 3), kc = (t & 7) * 8;
        *(s16x8*)&As[row][kc] = *(const s16x8*)(A + (size_t)(bm + row) * K + kt + kc);
      }
    } else {
      const float* A = (const float*)Aptr;
#pragma unroll
      for (int p = 0; p < 8; ++p) {
        int row = p * 16 + (t >> 4), kc = (t & 15) * 4;
        float4 f = *(const float4*)(A + (size_t)(bm + row) * K + kt + kc);
        unsigned* dst = (unsigned*)&As[row][kc];
        dst[0] = (unsigned)f2bf(f.x) | ((unsigned)f2bf(f.y) << 16);
        dst[1] = (unsigned)f2bf(f.z) | ((unsigned)f2bf(f.w) << 16);
      }
    }
    if (BBF16) {
      const u16* Bw = (const u16*)Bptr;
#pragma unroll
      for (int p = 0; p < 4; ++p) {
        int row = p * 32 + (t >> 3), kc = (t & 7) * 8;
        *(s16x8*)&Bs[row][kc] = *(const s16x8*)(Bw + (size_t)(bn + row) * K + kt + kc);
      }
    } else {
      const float* Bw = (const float*)Bptr;
#pragma unroll
      for (int p = 0; p < 8; ++p) {
        int row = p * 16 + (t >> 4), kc = (t & 15) * 4;
        float4 f = *(const float4*)(Bw + (size_t)(bn + row) * K + kt + kc);
        unsigned* dst = (unsigned*)&Bs[row][kc];
        dst[0] = (unsigned)f2bf(f.x) | ((unsigned)f2bf(f.y) << 16);
        dst[1] = (unsigned)f2bf(f.z) | ((unsigned)f2bf(f.w) << 16);
      }
    }
    __syncthreads();
#pragma unroll
    for (int ks = 0; ks < 2; ++ks) {
      s16x8 bfr[8];
#pragma unroll
      for (int nf = 0; nf < 8; ++nf)
        bfr[nf] = *(const s16x8*)&Bs[nf * 16 + l15][ks * 32 + lhi * 8];
#pragma unroll
      for (int mf = 0; mf < 2; ++mf) {
        s16x8 a = *(const s16x8*)&As[wave * 32 + mf * 16 + l15][ks * 32 + lhi * 8];
#pragma unroll
        for (int nf = 0; nf < 8; ++nf)
          acc[mf][nf] = __builtin_amdgcn_mfma_f32_16x16x32_bf16(a, bfr[nf], acc[mf][nf], 0, 0, 0);
      }
    }
  }

  if (EPI == 0) {
    float* C = (float*)outp;
#pragma unroll
    for (int mf = 0; mf < 2; ++mf)
#pragma unroll
      for (int nf = 0; nf < 8; ++nf) {
        int col = bn + nf * 16 + l15;
        int rb = bm + wave * 32 + mf * 16 + lhi * 4;
#pragma unroll
        for (int i = 0; i < 4; ++i) C[(size_t)(rb + i) * N + col] = acc[mf][nf][i];
      }
  } else if (EPI == 2) {
    u16* O = (u16*)outp;
    int h = bn >> 7;
#pragma unroll
    for (int mf = 0; mf < 2; ++mf)
#pragma unroll
      for (int nf = 0; nf < 4; ++nf) {
        int j = nf * 16 + l15;
        int rb = bm + wave * 32 + mf * 16 + lhi * 4;
#pragma unroll
        for (int i = 0; i < 4; ++i) {
          int m = rb + i;
          int b = m >> 11, srow = m & 2047;
          float c = cos_t[srow * 64 + j];
          float s = sin_t[srow * 64 + j];
          float x0 = acc[mf][nf][i];
          float x1 = acc[mf][nf + 4][i];
          size_t base = ((size_t)(b * Hh + h) * S_LEN + srow) * DHEAD;
          O[base + j] = f2bf(x0 * c - x1 * s);
          O[base + j + 64] = f2bf(x0 * s + x1 * c);
        }
      }
  } else {  // EPI == 4: bf16 transposed [b][h][d][s]
    u16* O = (u16*)outp;
#pragma unroll
    for (int mf = 0; mf < 2; ++mf)
#pragma unroll
      for (int nf = 0; nf < 8; ++nf) {
        int col = bn + nf * 16 + l15;
        int h = col >> 7, d = col & 127;
        int rb = bm + wave * 32 + mf * 16 + lhi * 4;
#pragma unroll
        for (int i = 0; i < 4; ++i) {
          int m = rb + i;
          int b = m >> 11, srow = m & 2047;
          O[((size_t)(b * Hh + h) * DHEAD + d) * S_LEN + srow] = f2bf(acc[mf][nf][i]);
        }
      }
  }
}

// ---------------- Flash attention (causal, GQA) ----------------
#define KIDX(r, c) (((r) * 128 + (c)) ^ (((r) & 7) << 3))
#define VIDX(d, kv) (((d) * 64 + (kv)) ^ (((d) & 7) << 3))
__global__ __launch_bounds__(512) void attn_kernel(
    const u16* __restrict__ q, const u16* __restrict__ k, const u16* __restrict__ vt,
    u16* __restrict__ ctx) {
  __shared__ u16 Ks[64 * 128];
  __shared__ u16 Vts[128 * 64];

  const int t = threadIdx.x;
  const int wave = t >> 6, lane = t & 63;
  const int l15 = lane & 15, lhi = lane >> 4;
  const int pi = blockIdx.x, h = blockIdx.y, b = blockIdx.z;
  const int kvh = h >> 2;
  const int qsub[2] = {pi, 15 - pi};
  const int ntiles = 32 - 2 * pi;

  const u16* qb = q + ((size_t)(b * NH_Q + h)) * S_LEN * DHEAD;
  const u16* kb = k + ((size_t)(b * NKV_H + kvh)) * S_LEN * DHEAD;
  const u16* vtb = vt + ((size_t)(b * NKV_H + kvh)) * DHEAD * S_LEN;

  s16x8 qf[2][4];
#pragma unroll
  for (int s = 0; s < 2; ++s)
#pragma unroll
    for (int ks = 0; ks < 4; ++ks)
      qf[s][ks] = *(const s16x8*)(qb + (size_t)(qsub[s] * 128 + wave * 16 + l15) * DHEAD +
                                  ks * 32 + lhi * 8);

  const f32x4 fz = {0.f, 0.f, 0.f, 0.f};
  f32x4 acc[2][8];
#pragma unroll
  for (int s = 0; s < 2; ++s)
#pragma unroll
    for (int i = 0; i < 8; ++i) acc[s][i] = fz;
  float mrow[2] = {-INFINITY, -INFINITY};
  float lsum[2] = {0.f, 0.f};

  const float scale = 0.08838834764831845f;

  const int sl0 = l15 | (((2 * lhi) & 3) << 4);
  const int sl1 = sl0 | 16;
  const bool hisel = (lhi & 2) != 0;

  const int krow = t >> 3, kd0 = (t & 7) * 16;
  const int vrow = t >> 2, vk0 = (t & 3) * 16;
  s16x8 kr0, kr1, vr0, vr1;
  {
    const u16* p = kb + (size_t)krow * DHEAD + kd0;
    kr0 = *(const s16x8*)p;
    kr1 = *(const s16x8*)(p + 8);
    const u16* pv = vtb + (size_t)vrow * S_LEN + vk0;
    vr0 = *(const s16x8*)pv;
    vr1 = *(const s16x8*)(pv + 8);
  }

  for (int tt = 0; tt < ntiles; ++tt) {
    __syncthreads();
    *(s16x8*)&Ks[KIDX(krow, kd0)] = kr0;
    *(s16x8*)&Ks[KIDX(krow, kd0 + 8)] = kr1;
    *(s16x8*)&Vts[VIDX(vrow, vk0)] = vr0;
    *(s16x8*)&Vts[VIDX(vrow, vk0 + 8)] = vr1;
    __syncthreads();
    if (tt + 1 < ntiles) {
      const u16* p = kb + (size_t)((tt + 1) * 64 + krow) * DHEAD + kd0;
      kr0 = *(const s16x8*)p;
      kr1 = *(const s16x8*)(p + 8);
      const u16* pv = vtb + (size_t)vrow * S_LEN + (tt + 1) * 64 + vk0;
      vr0 = *(const s16x8*)pv;
      vr1 = *(const s16x8*)(pv + 8);
    }

    const int kc_base = tt * 64;
#pragma unroll
    for (int s = 0; s < 2; ++s) {
      const int wmin = qsub[s] * 128 + wave * 16;
      if (kc_base > wmin + 15) continue;
      f32x4 sacc[4];
#pragma unroll
      for (int i = 0; i < 4; ++i) sacc[i] = fz;
      __builtin_amdgcn_s_setprio(1);
#pragma unroll
      for (int ks = 0; ks < 4; ++ks) {
#pragma unroll
        for (int nf = 0; nf < 4; ++nf) {
          s16x8 kf = *(const s16x8*)&Ks[KIDX(nf * 16 + l15, ks * 32 + lhi * 8)];
          sacc[nf] = __builtin_amdgcn_mfma_f32_16x16x32_bf16(kf, qf[s][ks], sacc[nf], 0, 0, 0);
        }
      }
      __builtin_amdgcn_s_setprio(0);

      const int qg = wmin + l15;
      float pmax = -INFINITY;
      if (kc_base + 63 > wmin) {
#pragma unroll
        for (int nf = 0; nf < 4; ++nf)
#pragma unroll
          for (int i = 0; i < 4; ++i) {
            int kv = kc_base + nf * 16 + lhi * 4 + i;
            float sv = sacc[nf][i] * scale;
            sv = (kv <= qg) ? sv : -INFINITY;
            sacc[nf][i] = sv;
            pmax = fmaxf(pmax, sv);
          }
      } else {
#pragma unroll
        for (int nf = 0; nf < 4; ++nf)
#pragma unroll
          for (int i = 0; i < 4; ++i) {
            float sv = sacc[nf][i] * scale;
            sacc[nf][i] = sv;
            pmax = fmaxf(pmax, sv);
          }
      }
      pmax = fmaxf(pmax, __shfl_xor(pmax, 16, 64));
      pmax = fmaxf(pmax, __shfl_xor(pmax, 32, 64));

      if (!__all(pmax <= mrow[s] + 8.0f)) {
        float mnew = fmaxf(mrow[s], pmax);
        float alpha = __expf(mrow[s] - mnew);
        mrow[s] = mnew;
        lsum[s] *= alpha;
#pragma unroll
        for (int i = 0; i < 4; ++i) {
          float al = __shfl(alpha, (lane & 48) | (lhi * 4 + i), 64);
#pragma unroll
          for (int df = 0; df < 8; ++df) acc[s][df][i] *= al;
        }
      }

      float rsum = 0.f;
      unsigned pk[4][2];
#pragma unroll
      for (int nf = 0; nf < 4; ++nf) {
        float p0 = __expf(sacc[nf][0] - mrow[s]);
        float p1 = __expf(sacc[nf][1] - mrow[s]);
        float p2 = __expf(sacc[nf][2] - mrow[s]);
        float p3 = __expf(sacc[nf][3] - mrow[s]);
        rsum += (p0 + p1) + (p2 + p3);
        pk[nf][0] = (unsigned)f2bf(p0) | ((unsigned)f2bf(p1) << 16);
        pk[nf][1] = (unsigned)f2bf(p2) | ((unsigned)f2bf(p3) << 16);
      }
      rsum += __shfl_xor(rsum, 16, 64);
      rsum += __shfl_xor(rsum, 32, 64);
      lsum[s] += rsum;

      s16x8 pa[2];
#pragma unroll
      for (int ph = 0; ph < 2; ++ph) {
        unsigned lo0 = __shfl((int)pk[2 * ph][0], sl0, 64);
        unsigned hi0 = __shfl((int)pk[2 * ph + 1][0], sl0, 64);
        unsigned lo1 = __shfl((int)pk[2 * ph][1], sl0, 64);
        unsigned hi1 = __shfl((int)pk[2 * ph + 1][1], sl0, 64);
        unsigned lo2 = __shfl((int)pk[2 * ph][0], sl1, 64);
        unsigned hi2 = __shfl((int)pk[2 * ph + 1][0], sl1, 64);
        unsigned lo3 = __shfl((int)pk[2 * ph][1], sl1, 64);
        unsigned hi3 = __shfl((int)pk[2 * ph + 1][1], sl1, 64);
        u32x4 w;
        w[0] = hisel ? hi0 : lo0;
        w[1] = hisel ? hi1 : lo1;
        w[2] = hisel ? hi2 : lo2;
        w[3] = hisel ? hi3 : lo3;
        pa[ph] = __builtin_bit_cast(s16x8, w);
      }

      __builtin_amdgcn_s_setprio(1);
#pragma unroll
      for (int ph = 0; ph < 2; ++ph) {
#pragma unroll
        for (int df = 0; df < 8; ++df) {
          s16x8 bb = *(const s16x8*)&Vts[VIDX(df * 16 + l15, ph * 32 + lhi * 8)];
          acc[s][df] = __builtin_amdgcn_mfma_f32_16x16x32_bf16(pa[ph], bb, acc[s][df], 0, 0, 0);
        }
      }
      __builtin_amdgcn_s_setprio(0);
    }
  }

#pragma unroll
  for (int s = 0; s < 2; ++s) {
    float rl = 1.0f / lsum[s];
#pragma unroll
    for (int i = 0; i < 4; ++i) {
      float rli = __shfl(rl, (lane & 48) | (lhi * 4 + i), 64);
      int m = b * S_LEN + qsub[s] * 128 + wave * 16 + lhi * 4 + i;
#pragma unroll
      for (int df = 0; df < 8; ++df) {
        int col = h * DHEAD + df * 16 + l15;
        ctx[(size_t)m * (NH_Q * DHEAD) + col] = f2bf(acc[s][df][i] * rli);
      }
    }
  }
}

extern "C" void kernel_launch(void* const* d_in, const int* in_sizes, int n_in,
                              void* d_out, int out_size, void* d_ws, size_t ws_size,
                              hipStream_t stream) {
  const float* x = (const float*)d_in[0];
  const int* positions = (const int*)d_in[1];
  const float* wq = (const float*)d_in[2];
  const float* wk = (const float*)d_in[3];
  const float* wv = (const float*)d_in[4];
  const float* wo = (const float*)d_in[5];
  float* out = (float*)d_out;

  char* ws = (char*)d_ws;
  const size_t MB1 = 1048576;
  const size_t SZ_X = 33554432;     // 2*2048*4096 bf16
  const size_t SZ_WQKV = 50331648;  // 6144*4096 bf16
  const size_t SZ_WO = 33554432;    // 4096*4096 bf16
  const size_t SZ_Q = 33554432;     // q bf16
  const size_t SZ_WK = 8388608;     // k or v bf16
  const size_t NEED_FULL = MB1 + SZ_X + SZ_WQKV + SZ_Q + 2 * SZ_WK;  // 129 MB
  const size_t NEED_WO = NEED_FULL + SZ_WO;                          // 161 MB

  float* cos_t = (float*)ws;
  float* sin_t = (float*)(ws + MB1 / 2);

  if (ws_size >= NEED_WO) {
    char* p = ws + MB1;
    u16* x_bf = (u16*)p;    p += SZ_X;     // later reused as ctx
    u16* wqkv_bf = (u16*)p; p += SZ_WQKV;  // wq|wk|wv stacked
    u16* wo_bf = (u16*)p;   p += SZ_WO;
    u16* q_ws = (u16*)p;    p += SZ_Q;     // q | k | v contiguous
    u16* k_ws = (u16*)p;    p += SZ_WK;
    u16* v_ws = (u16*)p;    p += SZ_WK;
    u16* ctx_ws = x_bf;

    cvt_all_kernel<<<2048, 256, 0, stream>>>(x, wq, wk, wv, wo, x_bf, wqkv_bf, wo_bf,
                                             positions, cos_t, sin_t, 1);
    // fused QKV: 128x256 tiles, grid (24,32) = 768 = 3 exact rounds
    gemmp_kernel<5><<<dim3(24, 32), 512, 0, stream>>>(
        x_bf, wqkv_bf, q_ws, 4096, 6144, 4096, cos_t, sin_t);
    attn_kernel<<<dim3(8, 32, 2), 512, 0, stream>>>(q_ws, k_ws, v_ws, ctx_ws);
    // out-proj: 256x256 tiles, grid (16,16) = 256 = 1 exact round
    gemmo_kernel<<<dim3(16, 16), 512, 0, stream>>>(
        ctx_ws, wo_bf, out, 4096, 4096, 4096);
  } else if (ws_size >= NEED_FULL) {
    char* p = ws + MB1;
    u16* x_bf = (u16*)p;    p += SZ_X;
    u16* wqkv_bf = (u16*)p; p += SZ_WQKV;
    u16* q_ws = (u16*)p;    p += SZ_Q;
    u16* k_ws = (u16*)p;    p += SZ_WK;
    u16* v_ws = (u16*)p;    p += SZ_WK;
    u16* ctx_ws = x_bf;

    cvt_all_kernel<<<2048, 256, 0, stream>>>(x, wq, wk, wv, nullptr, x_bf, wqkv_bf, nullptr,
                                             positions, cos_t, sin_t, 0);
    gemmp_kernel<5><<<dim3(24, 32), 512, 0, stream>>>(
        x_bf, wqkv_bf, q_ws, 4096, 6144, 4096, cos_t, sin_t);
    cvt_kernel<<<2048, 256, 0, stream>>>(wo, wqkv_bf, 4194304);  // wqkv_bf now = wo_bf
    attn_kernel<<<dim3(8, 32, 2), 512, 0, stream>>>(q_ws, k_ws, v_ws, ctx_ws);
    gemmo_kernel<<<dim3(16, 16), 512, 0, stream>>>(
        ctx_ws, wqkv_bf, out, 4096, 4096, 4096);
  } else {
    u16* q_ws = (u16*)(ws + MB1);
    u16* k_ws = (u16*)(ws + MB1 + SZ_Q);
    u16* v_ws = (u16*)(ws + MB1 + SZ_Q + SZ_WK);
    u16* ctx_ws = (u16*)(ws + MB1 + SZ_Q + 2 * SZ_WK);

    rope_table_kernel<<<512, 256, 0, stream>>>(positions, cos_t, sin_t);
    gemm_kernel<2, false, false><<<dim3(32, 32), 256, 0, stream>>>(
        x, wq, q_ws, nullptr, 4096, 4096, 4096, cos_t, sin_t, NH_Q);
    gemm_kernel<2, false, false><<<dim3(8, 32), 256, 0, stream>>>(
        x, wk, k_ws, nullptr, 4096, 1024, 4096, cos_t, sin_t, NKV_H);
    gemm_kernel<4, false, false><<<dim3(8, 32), 256, 0, stream>>>(
        x, wv, v_ws, nullptr, 4096, 1024, 4096, nullptr, nullptr, NKV_H);
    attn_kernel<<<dim3(8, 32, 2), 512, 0, stream>>>(q_ws, k_ws, v_ws, ctx_ws);
    gemm_kernel<0, true, false><<<dim3(32, 32), 256, 0, stream>>>(
        ctx_ws, wo, out, nullptr, 4096, 4096, 4096, nullptr, nullptr, 0);
  }
}